// Round 5
// baseline (674.812 us; speedup 1.0000x reference)
//
#include <hip/hip_runtime.h>
#include <hip/hip_bf16.h>
#include <cstdint>

// Problem dims
#define BB 16
#define CC 64
#define NN 512
#define TT 64
#define KCH 3
#define PP (BB*NN*TT)      // 524288 points
#define EPSB 1e-5f

typedef __bf16 bf16;
typedef __bf16 bf16x8 __attribute__((ext_vector_type(8)));
typedef __bf16 bf16x4 __attribute__((ext_vector_type(4)));
typedef float  f32x4  __attribute__((ext_vector_type(4)));

#define MFMA16(A,Bv,Cv) __builtin_amdgcn_mfma_f32_16x16x32_bf16((A),(Bv),(Cv),0,0,0)

__device__ __forceinline__ void gload_lds16(const bf16* g, bf16* l){
  __builtin_amdgcn_global_load_lds(
      (const __attribute__((address_space(1))) void*)g,
      (__attribute__((address_space(3))) void*)l, 16, 0, 0);
}

// ---------------- prep: adjb[k][n][m] = bf16(adj[k][m][n]) ----------------
__global__ __launch_bounds__(256) void k_adjT(const float* __restrict__ adj,
                                              bf16* __restrict__ adjb){
  int idx = blockIdx.x*256 + threadIdx.x;          // over 3*512*512, exact grid
  int m = idx & 511, n = (idx >> 9) & 511, k = idx >> 18;
  adjb[idx] = (bf16)adj[((size_t)(k*512 + m))*512 + n];
}

// ---------------- prep: weights into MFMA B-fragment layout ----------------
// consumer reads: frag elem j of lane l at step ks, colfrag cf:
//   B[k = ks*32 + (l>>4)*8 + j][col = cf*16 + (l&15)]
// stored at wp[(((ks*4+cf)*64 + l)*8 + j]
__global__ __launch_bounds__(256) void k_wprep(const float* __restrict__ w1,
    const float* __restrict__ w2, const float* __restrict__ cw,
    const float* __restrict__ gw, const float* __restrict__ rw,
    bf16* __restrict__ w1p, bf16* __restrict__ w2p, bf16* __restrict__ cp,
    bf16* __restrict__ gp, bf16* __restrict__ rp){
  int tid = threadIdx.x;
  for (int e = tid; e < 6*2048; e += 256){          // K=192 groups (conv & cheb)
    int j = e&7, lane = (e>>3)&63, cf = (e>>9)&3, ks = e>>11;
    int k = ks*32 + (lane>>4)*8 + j, col = cf*16 + (lane&15);
    int kk = k >> 6, i = k & 63;                    // (dt|chebk, channel)
    w1p[e] = (bf16)w1[(col*64 + i)*3 + kk];         // w1[o][i][dt]
    w2p[e] = (bf16)w2[(col*64 + i)*3 + kk];
    cp[e]  = (bf16)cw[((size_t)kk*64 + i)*64 + col];// cheb_w[k][i][o]
  }
  for (int e = tid; e < 4*2048; e += 256){          // K=128 (gate)
    int j = e&7, lane = (e>>3)&63, cf = (e>>9)&3, ks = e>>11;
    int k = ks*32 + (lane>>4)*8 + j, col = cf*16 + (lane&15);
    gp[e] = (bf16)gw[col*128 + k];                  // gate_w[g][c]
  }
  for (int e = tid; e < 2*2048; e += 256){          // K=64 (res)
    int j = e&7, lane = (e>>3)&63, cf = (e>>9)&3, ks = e>>11;
    int k = ks*32 + (lane>>4)*8 + j, col = cf*16 + (lane&15);
    rp[e] = (bf16)rw[col*64 + k];                   // res_w[o][i]
  }
}

// ---------------- prep: xlb[b][n][t][i] = bf16(x[b][i][n][t]) --------------
__global__ __launch_bounds__(256) void k_xlb(const float* __restrict__ x,
                                             bf16* __restrict__ xlb){
  __shared__ float tile[64][65];
  int bn = blockIdx.x; int b = bn >> 9, n = bn & 511;
  int tid = threadIdx.x;
  const float* xp = x + ((size_t)(b*64)*512 + n)*64;   // x[b][0][n][0]
  for (int p = 0; p < 4; ++p){
    int q = p*256 + tid;                  // quad id 0..1023
    int i = q >> 4, tc = (q & 15)*4;
    float4 v = *reinterpret_cast<const float4*>(xp + (size_t)i*512*64 + tc);
    tile[i][tc+0] = v.x; tile[i][tc+1] = v.y; tile[i][tc+2] = v.z; tile[i][tc+3] = v.w;
  }
  __syncthreads();
  bf16* op = xlb + (size_t)bn*4096;
  for (int p = 0; p < 2; ++p){
    int v8 = p*256 + tid;                 // 0..511
    int t = v8 >> 3, ic = (v8 & 7)*8;
    bf16x8 o;
    #pragma unroll
    for (int e = 0; e < 8; ++e) o[e] = (bf16)tile[ic+e][t];
    *reinterpret_cast<bf16x8*>(op + t*64 + ic) = o;
  }
}

// ---------------- prep: xmt[b][t][i][m] = bf16(x[b][i][m][t]) --------------
// tile: i:16, m:64, t:16
__global__ __launch_bounds__(256) void k_xmt(const float* __restrict__ x,
                                             bf16* __restrict__ xmt){
  __shared__ bf16 lds[16][16][72];        // [t][i][m+pad]
  int bid = blockIdx.x;
  int t0 = (bid & 3)*16, m0 = ((bid>>2)&7)*64, i0 = ((bid>>5)&3)*16, b = bid>>7;
  int tid = threadIdx.x;
  int tq = tid & 3, m = tid >> 2;         // 4 t-quads x 64 m
  for (int i = 0; i < 16; ++i){
    float4 v = *reinterpret_cast<const float4*>(
        x + ((size_t)(b*64 + i0 + i)*512 + (m0 + m))*64 + t0 + tq*4);
    lds[tq*4+0][i][m] = (bf16)v.x; lds[tq*4+1][i][m] = (bf16)v.y;
    lds[tq*4+2][i][m] = (bf16)v.z; lds[tq*4+3][i][m] = (bf16)v.w;
  }
  __syncthreads();
  for (int p = 0; p < 8; ++p){
    int row = p*32 + (tid >> 3); int t = row >> 4, i = row & 15, mc = tid & 7;
    bf16x8 v = *reinterpret_cast<const bf16x8*>(&lds[t][i][mc*8]);
    *reinterpret_cast<bf16x8*>(
        xmt + ((size_t)((b*64 + t0 + t)*64) + i0 + i)*512 + m0 + mc*8) = v;
  }
}

// ---------------- temporal conv (1x3) as tall GEMM; optional BN+relu on load
// in/out layout: [point=(b,n,t)][64ch]; block = one (b,n), 64 t x 64 o
__global__ __launch_bounds__(256,4) void k_conv(const bf16* __restrict__ in,
    const bf16* __restrict__ wp, bf16* __restrict__ outp, float* __restrict__ part,
    const float* __restrict__ sc, const float* __restrict__ sh){
  int tid = threadIdx.x, w = tid >> 6, l = tid & 63, l15 = l & 15, lg = l >> 4;
  int blk = blockIdx.x;
  size_t rowbase = (size_t)blk * 64;
  const bf16* xr = in + rowbase * 64;
  int t = w*16 + l15;
  f32x4 acc[4] = {};
  #pragma unroll
  for (int ks = 0; ks < 6; ++ks){
    int dt = ks >> 1, kh = ks & 1;
    int ts = t + dt - 1;
    bf16x8 a = {};
    if (ts >= 0 && ts < 64){
      a = *reinterpret_cast<const bf16x8*>(xr + ts*64 + kh*32 + lg*8);
      if (sc){                                  // BN1+relu applied on load
        int i0 = kh*32 + lg*8;
        #pragma unroll
        for (int e = 0; e < 8; ++e){
          float f = (float)a[e]*sc[i0+e] + sh[i0+e];
          a[e] = (bf16)fmaxf(f, 0.f);
        }
      }
    }
    #pragma unroll
    for (int cf = 0; cf < 4; ++cf){
      bf16x8 bfr = *reinterpret_cast<const bf16x8*>(wp + ((ks*4 + cf)*64 + l)*8);
      acc[cf] = MFMA16(a, bfr, acc[cf]);
    }
  }
  __shared__ float ssum[4][4][16], ssq[4][4][16];
  #pragma unroll
  for (int cf = 0; cf < 4; ++cf){
    int o = cf*16 + l15;
    float s = 0.f, q = 0.f;
    #pragma unroll
    for (int r = 0; r < 4; ++r){
      float vv = acc[cf][r];
      int to = w*16 + lg*4 + r;
      outp[(rowbase + to)*64 + o] = (bf16)vv;
      s += vv; q += vv*vv;
    }
    s += __shfl_xor(s, 16); s += __shfl_xor(s, 32);
    q += __shfl_xor(q, 16); q += __shfl_xor(q, 32);
    if (lg == 0){ ssum[w][cf][l15] = s; ssq[w][cf][l15] = q; }
  }
  __syncthreads();
  if (tid < 64){
    int cf = tid >> 4, c = tid & 15;
    float s = ssum[0][cf][c]+ssum[1][cf][c]+ssum[2][cf][c]+ssum[3][cf][c];
    float q = ssq[0][cf][c]+ssq[1][cf][c]+ssq[2][cf][c]+ssq[3][cf][c];
    part[(size_t)blk*128 + tid*2]     = s;
    part[(size_t)blk*128 + tid*2 + 1] = q;
  }
}

// ---------------- BN stats finalize: partials -> scale/shift ----------------
__global__ __launch_bounds__(256) void k_stats(const float* __restrict__ part, int nb,
    const float* __restrict__ g, const float* __restrict__ be,
    float* __restrict__ sc, float* __restrict__ sh){
  int c = blockIdx.x, tid = threadIdx.x;
  float s = 0.f, q = 0.f;
  for (int i = tid; i < nb; i += 256){
    s += part[(size_t)i*128 + c*2];
    q += part[(size_t)i*128 + c*2 + 1];
  }
  __shared__ float rs[256], rq[256];
  rs[tid] = s; rq[tid] = q; __syncthreads();
  for (int st = 128; st > 0; st >>= 1){
    if (tid < st){ rs[tid] += rs[tid+st]; rq[tid] += rq[tid+st]; }
    __syncthreads();
  }
  if (tid == 0){
    float cnt = (float)PP;
    float mean = rs[0]/cnt, var = rq[0]/cnt - mean*mean;
    float r = rsqrtf(var + EPSB);
    sc[c] = g[c]*r;
    sh[c] = be[c] - mean*g[c]*r;
  }
}

// ---------------- fused GEMM1+cheb: spm[(b,n,t)][o] ------------------------
// Per block: 128 j-rows (j=(b,t,i)) x 128 n. Flat 48-step loop over (kk,ks):
// chunk-major LDS [chunk4][row128][8] (conflict-free b128 reads), 3 buffers,
// 1-deep prefetch, ONE barrier + per-wave vmcnt fence per K-step. At each
// kk boundary: Vtile -> swizzled VT, cheb contraction over i -> acc2.
__global__ __launch_bounds__(256,2) void k_gemm1(const bf16* __restrict__ xmt,
    const bf16* __restrict__ adjb, const bf16* __restrict__ cp,
    const float* __restrict__ cb, bf16* __restrict__ spm){
  __shared__ bf16 As[3][4096];          // [buf][chunk(4)][row(128)][8]
  __shared__ bf16 Bs[3][4096];
  __shared__ bf16 VT[128*128];          // [n][j] swizzled; reused as SP[256][64]

  int tid = threadIdx.x, w = tid >> 6, l = tid & 63, l15 = l & 15, lg = l >> 4;
  int wr = w >> 1, wc = w & 1;

  // bijective XCD swizzle over 2048 blocks; nt innermost (A-panel shared by 4)
  int orig = blockIdx.x;
  int wg = (orig & 7) * 256 + (orig >> 3);
  int jt = wg >> 2, nt = wg & 3;
  int J0 = jt*128, N0 = nt*128;

  const bf16* aglob = xmt + (size_t)J0*512;
  const bf16* bbase = adjb + (size_t)N0*512;

  // stage tile t (t in [0,48)): kk = t>>4, m0 = (t&15)*32; 4 gloads (vmcnt +4)
  auto stage = [&](int t){
    int buf = t % 3;
    const bf16* bg = bbase + (size_t)(t >> 4)*512*512;
    int m0 = (t & 15)*32;
    #pragma unroll
    for (int p = 0; p < 2; ++p){
      int q = p*256 + tid;
      int r = q & 127, c = q >> 7;
      gload_lds16(aglob + (size_t)r*512 + m0 + c*8, &As[buf][q*8]);
      gload_lds16(bg    + (size_t)r*512 + m0 + c*8, &Bs[buf][q*8]);
    }
  };

  f32x4 acc2[4][4] = {};
  f32x4 acc[4][4] = {};
  int tw = w >> 1;                                // t_loc of this wave (cheb)

  stage(0);
  for (int t = 0; t < 48; ++t){
    if (t < 47){
      stage(t+1);
      asm volatile("s_waitcnt vmcnt(4)" ::: "memory");   // tile t staged
    } else {
      asm volatile("s_waitcnt vmcnt(0)" ::: "memory");
    }
    __builtin_amdgcn_s_barrier();
    __builtin_amdgcn_sched_barrier(0);

    int buf = t % 3;
    bf16x8 a[4], bb[4];
    #pragma unroll
    for (int rf = 0; rf < 4; ++rf){
      int row = wr*64 + rf*16 + l15;
      a[rf] = *reinterpret_cast<const bf16x8*>(&As[buf][(lg*128 + row)*8]);
    }
    #pragma unroll
    for (int cf = 0; cf < 4; ++cf){
      int row = wc*64 + cf*16 + l15;
      bb[cf] = *reinterpret_cast<const bf16x8*>(&Bs[buf][(lg*128 + row)*8]);
    }
    #pragma unroll
    for (int rf = 0; rf < 4; ++rf)
      #pragma unroll
      for (int cf = 0; cf < 4; ++cf)
        acc[rf][cf] = MFMA16(a[rf], bb[cf], acc[rf][cf]);

    if ((t & 15) == 15){
      int kk = t >> 4;
      // dump Vtile to VT[n][j], 16B-block-swizzled: block jb at jb^(n&15)
      #pragma unroll
      for (int rf = 0; rf < 4; ++rf){
        int jb = wr*8 + rf*2 + (lg >> 1);         // j0 = wr*64+rf*16+lg*4
        #pragma unroll
        for (int cf = 0; cf < 4; ++cf){
          int n = wc*64 + cf*16 + l15;
          bf16x4 pk;
          #pragma unroll
          for (int r = 0; r < 4; ++r) pk[r] = (bf16)acc[rf][cf][r];
          *reinterpret_cast<bf16x4*>(
              &VT[n*128 + ((jb ^ (n & 15)) << 3) + ((lg & 1) << 2)]) = pk;
          acc[rf][cf] = (f32x4){0.f, 0.f, 0.f, 0.f};
        }
      }
      // VT writes visible; do NOT drain vmcnt (prefetch of next kk survives)
      asm volatile("s_waitcnt lgkmcnt(0)" ::: "memory");
      __builtin_amdgcn_sched_barrier(0);
      __builtin_amdgcn_s_barrier();

      // cheb contraction: acc2[row=(t,n)][o] += VT^T(i) x cheb_w[kk]
      #pragma unroll
      for (int ks2 = 0; ks2 < 2; ++ks2){
        bf16x8 bc[4];
        #pragma unroll
        for (int cf = 0; cf < 4; ++cf)
          bc[cf] = *reinterpret_cast<const bf16x8*>(
              cp + (((kk*2 + ks2)*4 + cf)*64 + l)*8);
        #pragma unroll
        for (int rf = 0; rf < 4; ++rf){
          int n = (w & 1)*64 + rf*16 + l15;
          int jb = tw*8 + ks2*4 + lg;
          bf16x8 a2 = *reinterpret_cast<const bf16x8*>(
              &VT[n*128 + ((jb ^ (n & 15)) << 3)]);
          #pragma unroll
          for (int cf = 0; cf < 4; ++cf)
            acc2[rf][cf] = MFMA16(a2, bc[cf], acc2[rf][cf]);
        }
      }
      // VT reads retired before next kk's dump overwrites VT
      asm volatile("s_waitcnt lgkmcnt(0)" ::: "memory");
      __builtin_amdgcn_sched_barrier(0);
      __builtin_amdgcn_s_barrier();
    }
  }

  // epilogue: SP[row][o] = acc2 + cheb_b, then coalesced store
  bf16* SP = VT;
  float cbv[4];
  #pragma unroll
  for (int cf = 0; cf < 4; ++cf) cbv[cf] = cb[cf*16 + l15];
  #pragma unroll
  for (int rf = 0; rf < 4; ++rf){
    int rowb = w*64 + rf*16 + lg*4;
    #pragma unroll
    for (int cf = 0; cf < 4; ++cf){
      int o = cf*16 + l15;
      #pragma unroll
      for (int r = 0; r < 4; ++r)
        SP[(rowb + r)*64 + o] = (bf16)(acc2[rf][cf][r] + cbv[cf]);
    }
  }
  __syncthreads();
  int b = jt >> 5, t0 = (jt & 31)*2;
  #pragma unroll
  for (int q = 0; q < 8; ++q){
    int flat = q*256 + tid;                        // 2048 chunks of 8 elems
    int row = flat >> 3, oc = (flat & 7)*8;
    int tl = row >> 7, n = N0 + (row & 127);
    bf16x8 vv = *reinterpret_cast<const bf16x8*>(&SP[row*64 + oc]);
    *reinterpret_cast<bf16x8*>(
        &spm[(((size_t)b*512 + n)*64 + (t0 + tl))*64 + oc]) = vv;
  }
}

// ---------------- fusion: gate/res MFMA + combine; writes bf16 out_pre -----
__global__ __launch_bounds__(256,4) void k_fusion(const bf16* __restrict__ spm,
    const bf16* __restrict__ t2, const bf16* __restrict__ xlb,
    const bf16* __restrict__ gp, const bf16* __restrict__ rp,
    const float* __restrict__ sc2, const float* __restrict__ sh2,
    const float* __restrict__ gateb, bf16* __restrict__ pre,
    float* __restrict__ part){
  int tid = threadIdx.x, w = tid >> 6, l = tid & 63, l15 = l & 15, lg = l >> 4;
  int blk = blockIdx.x;
  int b = blk >> 9, n = blk & 511;
  size_t rowbase = (size_t)blk * 64;
  int t = w*16 + l15;
  f32x4 ag[4] = {}, ar[4] = {};
  #pragma unroll
  for (int ks = 0; ks < 4; ++ks){                 // gate: K=128 = [spatial|t2bn]
    bf16x8 a;
    if (ks < 2){
      a = *reinterpret_cast<const bf16x8*>(spm + (rowbase + t)*64 + ks*32 + lg*8);
    } else {
      int i0 = (ks-2)*32 + lg*8;
      bf16x8 raw = *reinterpret_cast<const bf16x8*>(t2 + (rowbase + t)*64 + i0);
      #pragma unroll
      for (int e = 0; e < 8; ++e){
        float f = (float)raw[e]*sc2[i0+e] + sh2[i0+e];
        a[e] = (bf16)fmaxf(f, 0.f);
      }
    }
    #pragma unroll
    for (int cf = 0; cf < 4; ++cf){
      bf16x8 bfr = *reinterpret_cast<const bf16x8*>(gp + ((ks*4 + cf)*64 + l)*8);
      ag[cf] = MFMA16(a, bfr, ag[cf]);
    }
  }
  #pragma unroll
  for (int ks = 0; ks < 2; ++ks){                 // res: K=64 on x
    bf16x8 a = *reinterpret_cast<const bf16x8*>(xlb + (rowbase + t)*64 + ks*32 + lg*8);
    #pragma unroll
    for (int cf = 0; cf < 4; ++cf){
      bf16x8 bfr = *reinterpret_cast<const bf16x8*>(rp + ((ks*4 + cf)*64 + l)*8);
      ar[cf] = MFMA16(a, bfr, ar[cf]);
    }
  }
  __shared__ float ssum[4][4][16], ssq[4][4][16];
  int tb = w*16 + lg*4;
  #pragma unroll
  for (int cf = 0; cf < 4; ++cf){
    int o = cf*16 + l15;
    float gb = gateb[o], sco = sc2[o], sho = sh2[o];
    float s = 0.f, q = 0.f;
    bf16x4 ov;
    #pragma unroll
    for (int r = 0; r < 4; ++r){
      size_t row = rowbase + tb + r;
      float z = ag[cf][r] + gb;
      float g = 1.f/(1.f + __expf(-z));
      float spv = (float)spm[row*64 + o];
      float tv  = (float)t2[row*64 + o];
      tv = fmaxf(tv*sco + sho, 0.f);
      float val = g*spv + (1.f - g)*tv + ar[cf][r];
      ov[r] = (bf16)val;
      s += val; q += val*val;
    }
    *reinterpret_cast<bf16x4*>(pre + (((size_t)b*64 + o)*512 + n)*64 + tb) = ov;
    s += __shfl_xor(s, 16); s += __shfl_xor(s, 32);
    q += __shfl_xor(q, 16); q += __shfl_xor(q, 32);
    if (lg == 0){ ssum[w][cf][l15] = s; ssq[w][cf][l15] = q; }
  }
  __syncthreads();
  if (tid < 64){
    int cf = tid >> 4, c = tid & 15;
    float s = ssum[0][cf][c]+ssum[1][cf][c]+ssum[2][cf][c]+ssum[3][cf][c];
    float q = ssq[0][cf][c]+ssq[1][cf][c]+ssq[2][cf][c]+ssq[3][cf][c];
    part[(size_t)blk*128 + tid*2]     = s;
    part[(size_t)blk*128 + tid*2 + 1] = q;
  }
}

// ---------------- BN3: read bf16 out_pre, write fp32 d_out ------------------
__global__ __launch_bounds__(256) void k_bn3(const bf16* __restrict__ pre,
    float* __restrict__ out,
    const float* __restrict__ sc, const float* __restrict__ sh){
  size_t total8 = (size_t)BB*CC*NN*TT/8;
  for (size_t i8 = (size_t)blockIdx.x*256 + threadIdx.x; i8 < total8;
       i8 += (size_t)gridDim.x*256){
    bf16x8 v = reinterpret_cast<const bf16x8*>(pre)[i8];
    int o = (int)(i8 >> 12) & 63;                  // n*t = 32768 per (b,o)
    float a = sc[o], bsh = sh[o];
    float4 r0, r1;
    r0.x = (float)v[0]*a + bsh; r0.y = (float)v[1]*a + bsh;
    r0.z = (float)v[2]*a + bsh; r0.w = (float)v[3]*a + bsh;
    r1.x = (float)v[4]*a + bsh; r1.y = (float)v[5]*a + bsh;
    r1.z = (float)v[6]*a + bsh; r1.w = (float)v[7]*a + bsh;
    reinterpret_cast<float4*>(out)[i8*2]     = r0;
    reinterpret_cast<float4*>(out)[i8*2 + 1] = r1;
  }
}

extern "C" void kernel_launch(void* const* d_in, const int* in_sizes, int n_in,
                              void* d_out, int out_size, void* d_ws, size_t ws_size,
                              hipStream_t stream){
  (void)in_sizes; (void)n_in; (void)out_size; (void)ws_size;
  const float* x   = (const float*)d_in[0];
  const float* adj = (const float*)d_in[1];
  const float* cw  = (const float*)d_in[2];
  const float* cb  = (const float*)d_in[3];
  const float* w1  = (const float*)d_in[4];
  // d_in[5] = b1 (cancels in BN1)
  const float* g1  = (const float*)d_in[6];
  const float* be1 = (const float*)d_in[7];
  const float* w2  = (const float*)d_in[8];
  // d_in[9] = b2 (cancels in BN2)
  const float* g2  = (const float*)d_in[10];
  const float* be2 = (const float*)d_in[11];
  const float* gw  = (const float*)d_in[12];
  const float* gb  = (const float*)d_in[13];
  const float* rw  = (const float*)d_in[14];
  // d_in[15] = res_b (cancels in BN3)
  const float* g3  = (const float*)d_in[16];
  const float* be3 = (const float*)d_in[17];
  float* out = (float*)d_out;

  char* ws = (char*)d_ws;
  size_t off = 0;
  auto alloc = [&](size_t bytes)->char*{
    char* p = ws + off; off += (bytes + 255) & ~(size_t)255; return p;
  };
  bf16* xlb  = (bf16*)alloc((size_t)PP*64*2);        // 67MB channel-last x
  bf16* xmt  = (bf16*)alloc((size_t)PP*64*2);        // 67MB; reused as out_pre
  bf16* t1   = (bf16*)alloc((size_t)PP*64*2);        // 67MB; reused as spm
  bf16* t2   = (bf16*)alloc((size_t)PP*64*2);        // 67MB
  bf16* spm  = t1;                                   // alias (t1 dead after conv2)
  bf16* pre  = xmt;                                  // alias (xmt dead after gemm1)
  bf16* adjb = (bf16*)alloc((size_t)KCH*512*512*2);
  bf16* w1p  = (bf16*)alloc(6*2048*2);
  bf16* w2p  = (bf16*)alloc(6*2048*2);
  bf16* cp   = (bf16*)alloc(6*2048*2);
  bf16* gp   = (bf16*)alloc(4*2048*2);
  bf16* rp   = (bf16*)alloc(2*2048*2);
  float* part = (float*)alloc((size_t)8192*128*4);   // shared partials (sequential)
  float* s1sc = (float*)alloc(256); float* s1sh = (float*)alloc(256);
  float* s2sc = (float*)alloc(256); float* s2sh = (float*)alloc(256);
  float* s3sc = (float*)alloc(256); float* s3sh = (float*)alloc(256);

  k_adjT <<<dim3(3072), dim3(256), 0, stream>>>(adj, adjb);
  k_wprep<<<dim3(1),    dim3(256), 0, stream>>>(w1, w2, cw, gw, rw, w1p, w2p, cp, gp, rp);
  k_xlb  <<<dim3(8192), dim3(256), 0, stream>>>(x, xlb);
  k_xmt  <<<dim3(2048), dim3(256), 0, stream>>>(x, xmt);

  k_conv <<<dim3(8192), dim3(256), 0, stream>>>(xlb, w1p, t1, part, nullptr, nullptr);
  k_stats<<<dim3(64),   dim3(256), 0, stream>>>(part, 8192, g1, be1, s1sc, s1sh);
  k_conv <<<dim3(8192), dim3(256), 0, stream>>>(t1, w2p, t2, part, s1sc, s1sh);
  k_stats<<<dim3(64),   dim3(256), 0, stream>>>(part, 8192, g2, be2, s2sc, s2sh);

  k_gemm1<<<dim3(2048), dim3(256), 0, stream>>>(xmt, adjb, cp, cb, spm);

  k_fusion<<<dim3(8192), dim3(256), 0, stream>>>(spm, t2, xlb, gp, rp,
                                                 s2sc, s2sh, gb, pre, part);
  k_stats<<<dim3(64),   dim3(256), 0, stream>>>(part, 8192, g3, be3, s3sc, s3sh);
  k_bn3  <<<dim3(2048), dim3(256), 0, stream>>>(pre, out, s3sc, s3sh);
}

// Round 6
// 656.171 us; speedup vs baseline: 1.0284x; 1.0284x over previous
//
#include <hip/hip_runtime.h>
#include <hip/hip_bf16.h>
#include <cstdint>

// Problem dims
#define BB 16
#define CC 64
#define NN 512
#define TT 64
#define KCH 3
#define PP (BB*NN*TT)      // 524288 points
#define EPSB 1e-5f

typedef __bf16 bf16;
typedef __bf16 bf16x8 __attribute__((ext_vector_type(8)));
typedef __bf16 bf16x4 __attribute__((ext_vector_type(4)));
typedef float  f32x4  __attribute__((ext_vector_type(4)));

#define MFMA16(A,Bv,Cv) __builtin_amdgcn_mfma_f32_16x16x32_bf16((A),(Bv),(Cv),0,0,0)

__device__ __forceinline__ void gload_lds16(const bf16* g, bf16* l){
  __builtin_amdgcn_global_load_lds(
      (const __attribute__((address_space(1))) void*)g,
      (__attribute__((address_space(3))) void*)l, 16, 0, 0);
}

// ---------------- prep: adjb[k][n][m] = bf16(adj[k][m][n]) ----------------
__global__ __launch_bounds__(256) void k_adjT(const float* __restrict__ adj,
                                              bf16* __restrict__ adjb){
  int idx = blockIdx.x*256 + threadIdx.x;          // over 3*512*512, exact grid
  int m = idx & 511, n = (idx >> 9) & 511, k = idx >> 18;
  adjb[idx] = (bf16)adj[((size_t)(k*512 + m))*512 + n];
}

// ---------------- prep: weights into MFMA B-fragment layout ----------------
__global__ __launch_bounds__(256) void k_wprep(const float* __restrict__ w1,
    const float* __restrict__ w2, const float* __restrict__ cw,
    const float* __restrict__ gw, const float* __restrict__ rw,
    bf16* __restrict__ w1p, bf16* __restrict__ w2p, bf16* __restrict__ cp,
    bf16* __restrict__ gp, bf16* __restrict__ rp){
  int tid = threadIdx.x;
  for (int e = tid; e < 6*2048; e += 256){          // K=192 groups (conv & cheb)
    int j = e&7, lane = (e>>3)&63, cf = (e>>9)&3, ks = e>>11;
    int k = ks*32 + (lane>>4)*8 + j, col = cf*16 + (lane&15);
    int kk = k >> 6, i = k & 63;                    // (dt|chebk, channel)
    w1p[e] = (bf16)w1[(col*64 + i)*3 + kk];         // w1[o][i][dt]
    w2p[e] = (bf16)w2[(col*64 + i)*3 + kk];
    cp[e]  = (bf16)cw[((size_t)kk*64 + i)*64 + col];// cheb_w[k][i][o]
  }
  for (int e = tid; e < 4*2048; e += 256){          // K=128 (gate)
    int j = e&7, lane = (e>>3)&63, cf = (e>>9)&3, ks = e>>11;
    int k = ks*32 + (lane>>4)*8 + j, col = cf*16 + (lane&15);
    gp[e] = (bf16)gw[col*128 + k];                  // gate_w[g][c]
  }
  for (int e = tid; e < 2*2048; e += 256){          // K=64 (res)
    int j = e&7, lane = (e>>3)&63, cf = (e>>9)&3, ks = e>>11;
    int k = ks*32 + (lane>>4)*8 + j, col = cf*16 + (lane&15);
    rp[e] = (bf16)rw[col*64 + k];                   // res_w[o][i]
  }
}

// ---------------- prep: xlb[b][n][t][i] = bf16(x[b][i][n][t]) --------------
__global__ __launch_bounds__(256) void k_xlb(const float* __restrict__ x,
                                             bf16* __restrict__ xlb){
  __shared__ float tile[64][65];
  int bn = blockIdx.x; int b = bn >> 9, n = bn & 511;
  int tid = threadIdx.x;
  const float* xp = x + ((size_t)(b*64)*512 + n)*64;   // x[b][0][n][0]
  for (int p = 0; p < 4; ++p){
    int q = p*256 + tid;                  // quad id 0..1023
    int i = q >> 4, tc = (q & 15)*4;
    float4 v = *reinterpret_cast<const float4*>(xp + (size_t)i*512*64 + tc);
    tile[i][tc+0] = v.x; tile[i][tc+1] = v.y; tile[i][tc+2] = v.z; tile[i][tc+3] = v.w;
  }
  __syncthreads();
  bf16* op = xlb + (size_t)bn*4096;
  for (int p = 0; p < 2; ++p){
    int v8 = p*256 + tid;                 // 0..511
    int t = v8 >> 3, ic = (v8 & 7)*8;
    bf16x8 o;
    #pragma unroll
    for (int e = 0; e < 8; ++e) o[e] = (bf16)tile[ic+e][t];
    *reinterpret_cast<bf16x8*>(op + t*64 + ic) = o;
  }
}

// ---------------- prep: xmt[b][t][i][m] = bf16(x[b][i][m][t]) --------------
// v2: tile (i:8, m:64, t:64). Reads: full 256B t-rows. LDS: row im=i*64+m of
// 16 8B-slots, slot XOR-swizzled by ((m^i)&15) -> conflict-free writes,
// ~4-way reads. Writes: 128B contiguous m-chunks.
__global__ __launch_bounds__(256) void k_xmt(const float* __restrict__ x,
                                             bf16* __restrict__ xmt){
  __shared__ bf16 T[32768];               // 64KB: [im(512)][slot(16)][4]
  int bid = blockIdx.x;
  int b = bid >> 6, i0 = ((bid >> 3) & 7)*8, m0 = (bid & 7)*64;
  int tid = threadIdx.x;
  #pragma unroll 4
  for (int it = 0; it < 32; ++it){
    int flat = it*256 + tid;              // [0,8192)
    int t4 = flat & 15, m = (flat >> 4) & 63, i = flat >> 10;
    float4 v = *reinterpret_cast<const float4*>(
        x + ((size_t)((b*64 + i0 + i)*512) + (m0 + m))*64 + t4*4);
    int im = i*64 + m;
    int slot = t4 ^ ((m ^ i) & 15);
    bf16x4 pk; pk[0] = (bf16)v.x; pk[1] = (bf16)v.y; pk[2] = (bf16)v.z; pk[3] = (bf16)v.w;
    *reinterpret_cast<bf16x4*>(&T[im*64 + slot*4]) = pk;
  }
  __syncthreads();
  #pragma unroll 4
  for (int it = 0; it < 16; ++it){
    int flat = it*256 + tid;              // [0,4096)
    int mc = flat & 7, i = (flat >> 3) & 7, t = flat >> 6;
    bf16x8 o;
    #pragma unroll
    for (int e = 0; e < 8; ++e){
      int m = mc*8 + e;
      int slot = (t >> 2) ^ ((m ^ i) & 15);
      o[e] = T[(i*64 + m)*64 + slot*4 + (t & 3)];
    }
    *reinterpret_cast<bf16x8*>(
        &xmt[((size_t)((b*64 + t)*64) + i0 + i)*512 + m0 + mc*8]) = o;
  }
}

// ---------------- temporal conv (1x3) as tall GEMM; optional BN+relu on load
__global__ __launch_bounds__(256,4) void k_conv(const bf16* __restrict__ in,
    const bf16* __restrict__ wp, bf16* __restrict__ outp, float* __restrict__ part,
    const float* __restrict__ sc, const float* __restrict__ sh){
  int tid = threadIdx.x, w = tid >> 6, l = tid & 63, l15 = l & 15, lg = l >> 4;
  int blk = blockIdx.x;
  size_t rowbase = (size_t)blk * 64;
  const bf16* xr = in + rowbase * 64;
  int t = w*16 + l15;
  f32x4 acc[4] = {};
  #pragma unroll
  for (int ks = 0; ks < 6; ++ks){
    int dt = ks >> 1, kh = ks & 1;
    int ts = t + dt - 1;
    bf16x8 a = {};
    if (ts >= 0 && ts < 64){
      a = *reinterpret_cast<const bf16x8*>(xr + ts*64 + kh*32 + lg*8);
      if (sc){                                  // BN1+relu applied on load
        int i0 = kh*32 + lg*8;
        #pragma unroll
        for (int e = 0; e < 8; ++e){
          float f = (float)a[e]*sc[i0+e] + sh[i0+e];
          a[e] = (bf16)fmaxf(f, 0.f);
        }
      }
    }
    #pragma unroll
    for (int cf = 0; cf < 4; ++cf){
      bf16x8 bfr = *reinterpret_cast<const bf16x8*>(wp + ((ks*4 + cf)*64 + l)*8);
      acc[cf] = MFMA16(a, bfr, acc[cf]);
    }
  }
  __shared__ float ssum[4][4][16], ssq[4][4][16];
  #pragma unroll
  for (int cf = 0; cf < 4; ++cf){
    int o = cf*16 + l15;
    float s = 0.f, q = 0.f;
    #pragma unroll
    for (int r = 0; r < 4; ++r){
      float vv = acc[cf][r];
      int to = w*16 + lg*4 + r;
      outp[(rowbase + to)*64 + o] = (bf16)vv;
      s += vv; q += vv*vv;
    }
    s += __shfl_xor(s, 16); s += __shfl_xor(s, 32);
    q += __shfl_xor(q, 16); q += __shfl_xor(q, 32);
    if (lg == 0){ ssum[w][cf][l15] = s; ssq[w][cf][l15] = q; }
  }
  __syncthreads();
  if (tid < 64){
    int cf = tid >> 4, c = tid & 15;
    float s = ssum[0][cf][c]+ssum[1][cf][c]+ssum[2][cf][c]+ssum[3][cf][c];
    float q = ssq[0][cf][c]+ssq[1][cf][c]+ssq[2][cf][c]+ssq[3][cf][c];
    part[(size_t)blk*128 + tid*2]     = s;
    part[(size_t)blk*128 + tid*2 + 1] = q;
  }
}

// ---------------- BN stats finalize: partials -> scale/shift ----------------
__global__ __launch_bounds__(256) void k_stats(const float* __restrict__ part, int nb,
    const float* __restrict__ g, const float* __restrict__ be,
    float* __restrict__ sc, float* __restrict__ sh){
  int c = blockIdx.x, tid = threadIdx.x;
  float s = 0.f, q = 0.f;
  for (int i = tid; i < nb; i += 256){
    s += part[(size_t)i*128 + c*2];
    q += part[(size_t)i*128 + c*2 + 1];
  }
  __shared__ float rs[256], rq[256];
  rs[tid] = s; rq[tid] = q; __syncthreads();
  for (int st = 128; st > 0; st >>= 1){
    if (tid < st){ rs[tid] += rs[tid+st]; rq[tid] += rq[tid+st]; }
    __syncthreads();
  }
  if (tid == 0){
    float cnt = (float)PP;
    float mean = rs[0]/cnt, var = rq[0]/cnt - mean*mean;
    float r = rsqrtf(var + EPSB);
    sc[c] = g[c]*r;
    sh[c] = be[c] - mean*g[c]*r;
  }
}

// ---------------- fused GEMM1+cheb: spm[(b,n,t)][o] ------------------------
// 48KB LDS (2-buf staging 32KB + 16KB half-VT) -> 3 blocks/CU. Round-4
// staging/read pattern (64B-coalesced global, XOR chunk swizzle). Counted
// vmcnt(4) + raw barriers; next-kk tile0 prefetch rides through cheb phases.
// Cheb contraction + epilogue processed in two n-halves through the 16KB VT.
__global__ __launch_bounds__(256,3) void k_gemm1(const bf16* __restrict__ xmt,
    const bf16* __restrict__ adjb, const bf16* __restrict__ cp,
    const float* __restrict__ cb, bf16* __restrict__ spm){
  __shared__ bf16 As[2][4096];          // [buf][row128][chunk4 XOR-swz][8]
  __shared__ bf16 Bs[2][4096];
  __shared__ bf16 VT[64*128];           // 16KB half-tile; reused as SP[128][64]

  int tid = threadIdx.x, w = tid >> 6, l = tid & 63, l15 = l & 15, lg = l >> 4;
  int wr = w >> 1, wc = w & 1;

  // bijective XCD swizzle over 2048 blocks; nt innermost (A-panel shared by 4)
  int orig = blockIdx.x;
  int wg = (orig & 7) * 256 + (orig >> 3);
  int jt = wg >> 2, nt = wg & 3;
  int J0 = jt*128, N0 = nt*128;

  const bf16* aglob = xmt + (size_t)J0*512;
  const bf16* bbase = adjb + (size_t)N0*512;

  // stage tile t (t in [0,48)): buf = t&1; 4 gload instrs per wave (vmcnt +4)
  auto stage = [&](int t){
    int buf = t & 1;
    const bf16* bg = bbase + (size_t)(t >> 4)*512*512;
    int m0 = (t & 15)*32;
    #pragma unroll
    for (int p = 0; p < 2; ++p){
      int idx = p*256 + tid;
      int r = idx >> 2, c = idx & 3;
      int cg = c ^ (r & 3);
      gload_lds16(aglob + (size_t)r*512 + m0 + cg*8,
                  &As[buf][(p*256 + w*64)*8]);
      gload_lds16(bg + (size_t)r*512 + m0 + cg*8,
                  &Bs[buf][(p*256 + w*64)*8]);
    }
  };

  f32x4 acc[4][4] = {};
  f32x4 acc2[4][4] = {};

  stage(0);
  for (int t = 0; t < 48; ++t){
    if (t < 47){
      stage(t+1);
      asm volatile("s_waitcnt vmcnt(4)" ::: "memory");   // tile t landed
    } else {
      asm volatile("s_waitcnt vmcnt(0)" ::: "memory");
    }
    __builtin_amdgcn_s_barrier();
    __builtin_amdgcn_sched_barrier(0);

    int buf = t & 1;
    bf16x8 a[4], bb[4];
    #pragma unroll
    for (int rf = 0; rf < 4; ++rf){
      int row = wr*64 + rf*16 + l15;
      a[rf] = *reinterpret_cast<const bf16x8*>(
          &As[buf][row*32 + ((lg ^ (row & 3))*8)]);
    }
    #pragma unroll
    for (int cf = 0; cf < 4; ++cf){
      int row = wc*64 + cf*16 + l15;
      bb[cf] = *reinterpret_cast<const bf16x8*>(
          &Bs[buf][row*32 + ((lg ^ (row & 3))*8)]);
    }
    #pragma unroll
    for (int rf = 0; rf < 4; ++rf)
      #pragma unroll
      for (int cf = 0; cf < 4; ++cf)
        acc[rf][cf] = MFMA16(a[rf], bb[cf], acc[rf][cf]);

    // seal this buffer's reads before next iter's stage overwrites it
    asm volatile("s_waitcnt lgkmcnt(0)" ::: "memory");
    __builtin_amdgcn_sched_barrier(0);
    __builtin_amdgcn_s_barrier();

    if ((t & 15) == 15){
      int kk = t >> 4;
      #pragma unroll
      for (int h = 0; h < 2; ++h){
        // dump half h (n in [h*64, h*64+64)) by waves with wc==h
        if (wc == h){
          #pragma unroll
          for (int rf = 0; rf < 4; ++rf){
            int jb = wr*8 + rf*2 + (lg >> 1);
            #pragma unroll
            for (int cf = 0; cf < 4; ++cf){
              int nh = cf*16 + l15;
              bf16x4 pk;
              #pragma unroll
              for (int r = 0; r < 4; ++r) pk[r] = (bf16)acc[rf][cf][r];
              *reinterpret_cast<bf16x4*>(
                  &VT[nh*128 + ((jb ^ (nh & 15)) << 3) + ((lg & 1) << 2)]) = pk;
            }
          }
        }
        asm volatile("s_waitcnt lgkmcnt(0)" ::: "memory");
        __builtin_amdgcn_sched_barrier(0);
        __builtin_amdgcn_s_barrier();

        // contract: all 4 waves; wave w rows (t_out=w>>1, nh=(w&1)*32+rf2*16+l15)
        #pragma unroll
        for (int ks2 = 0; ks2 < 2; ++ks2){
          bf16x8 bc[4];
          #pragma unroll
          for (int cf = 0; cf < 4; ++cf)
            bc[cf] = *reinterpret_cast<const bf16x8*>(
                cp + (((kk*2 + ks2)*4 + cf)*64 + l)*8);
          #pragma unroll
          for (int rf2 = 0; rf2 < 2; ++rf2){
            int nh = (w & 1)*32 + rf2*16 + l15;
            int jb = (w >> 1)*8 + ks2*4 + lg;
            bf16x8 a2 = *reinterpret_cast<const bf16x8*>(
                &VT[nh*128 + ((jb ^ (nh & 15)) << 3)]);
            #pragma unroll
            for (int cf = 0; cf < 4; ++cf)
              acc2[h*2 + rf2][cf] = MFMA16(a2, bc[cf], acc2[h*2 + rf2][cf]);
          }
        }
        asm volatile("s_waitcnt lgkmcnt(0)" ::: "memory");
        __builtin_amdgcn_sched_barrier(0);
        __builtin_amdgcn_s_barrier();
      }
      // reset main accumulator for next kk
      #pragma unroll
      for (int rf = 0; rf < 4; ++rf)
        #pragma unroll
        for (int cf = 0; cf < 4; ++cf)
          acc[rf][cf] = (f32x4){0.f, 0.f, 0.f, 0.f};
    }
  }

  // epilogue in two t-halves through SP=VT (16KB = [n:128][o:64])
  bf16* SP = VT;
  float cbv[4];
  #pragma unroll
  for (int cf = 0; cf < 4; ++cf) cbv[cf] = cb[cf*16 + l15];
  int b = jt >> 5, t0 = (jt & 31)*2;
  #pragma unroll
  for (int hr = 0; hr < 2; ++hr){
    if ((w >> 1) == hr){                  // waves owning t_out == hr
      #pragma unroll
      for (int f = 0; f < 4; ++f){
        int h = f >> 1, rf2 = f & 1;
        int rowb = h*64 + (w & 1)*32 + rf2*16 + lg*4;   // n within [0,128)
        #pragma unroll
        for (int cf = 0; cf < 4; ++cf){
          int o = cf*16 + l15;
          #pragma unroll
          for (int r = 0; r < 4; ++r)
            SP[(rowb + r)*64 + o] = (bf16)(acc2[f][cf][r] + cbv[cf]);
        }
      }
    }
    __syncthreads();
    #pragma unroll
    for (int q = 0; q < 4; ++q){
      int flat = q*256 + tid;             // 1024 chunks of 8 elems
      int n = flat >> 3, oc = (flat & 7)*8;
      bf16x8 vv = *reinterpret_cast<const bf16x8*>(&SP[n*64 + oc]);
      *reinterpret_cast<bf16x8*>(
          &spm[(((size_t)b*512 + N0 + n)*64 + (t0 + hr))*64 + oc]) = vv;
    }
    __syncthreads();
  }
}

// ---------------- fusion: gate/res MFMA + combine; writes bf16 out_pre -----
__global__ __launch_bounds__(256,4) void k_fusion(const bf16* __restrict__ spm,
    const bf16* __restrict__ t2, const bf16* __restrict__ xlb,
    const bf16* __restrict__ gp, const bf16* __restrict__ rp,
    const float* __restrict__ sc2, const float* __restrict__ sh2,
    const float* __restrict__ gateb, bf16* __restrict__ pre,
    float* __restrict__ part){
  int tid = threadIdx.x, w = tid >> 6, l = tid & 63, l15 = l & 15, lg = l >> 4;
  int blk = blockIdx.x;
  int b = blk >> 9, n = blk & 511;
  size_t rowbase = (size_t)blk * 64;
  int t = w*16 + l15;
  f32x4 ag[4] = {}, ar[4] = {};
  #pragma unroll
  for (int ks = 0; ks < 4; ++ks){                 // gate: K=128 = [spatial|t2bn]
    bf16x8 a;
    if (ks < 2){
      a = *reinterpret_cast<const bf16x8*>(spm + (rowbase + t)*64 + ks*32 + lg*8);
    } else {
      int i0 = (ks-2)*32 + lg*8;
      bf16x8 raw = *reinterpret_cast<const bf16x8*>(t2 + (rowbase + t)*64 + i0);
      #pragma unroll
      for (int e = 0; e < 8; ++e){
        float f = (float)raw[e]*sc2[i0+e] + sh2[i0+e];
        a[e] = (bf16)fmaxf(f, 0.f);
      }
    }
    #pragma unroll
    for (int cf = 0; cf < 4; ++cf){
      bf16x8 bfr = *reinterpret_cast<const bf16x8*>(gp + ((ks*4 + cf)*64 + l)*8);
      ag[cf] = MFMA16(a, bfr, ag[cf]);
    }
  }
  #pragma unroll
  for (int ks = 0; ks < 2; ++ks){                 // res: K=64 on x
    bf16x8 a = *reinterpret_cast<const bf16x8*>(xlb + (rowbase + t)*64 + ks*32 + lg*8);
    #pragma unroll
    for (int cf = 0; cf < 4; ++cf){
      bf16x8 bfr = *reinterpret_cast<const bf16x8*>(rp + ((ks*4 + cf)*64 + l)*8);
      ar[cf] = MFMA16(a, bfr, ar[cf]);
    }
  }
  __shared__ float ssum[4][4][16], ssq[4][4][16];
  int tb = w*16 + lg*4;
  #pragma unroll
  for (int cf = 0; cf < 4; ++cf){
    int o = cf*16 + l15;
    float gb = gateb[o], sco = sc2[o], sho = sh2[o];
    float s = 0.f, q = 0.f;
    bf16x4 ov;
    #pragma unroll
    for (int r = 0; r < 4; ++r){
      size_t row = rowbase + tb + r;
      float z = ag[cf][r] + gb;
      float g = 1.f/(1.f + __expf(-z));
      float spv = (float)spm[row*64 + o];
      float tv  = (float)t2[row*64 + o];
      tv = fmaxf(tv*sco + sho, 0.f);
      float val = g*spv + (1.f - g)*tv + ar[cf][r];
      ov[r] = (bf16)val;
      s += val; q += val*val;
    }
    *reinterpret_cast<bf16x4*>(pre + (((size_t)b*64 + o)*512 + n)*64 + tb) = ov;
    s += __shfl_xor(s, 16); s += __shfl_xor(s, 32);
    q += __shfl_xor(q, 16); q += __shfl_xor(q, 32);
    if (lg == 0){ ssum[w][cf][l15] = s; ssq[w][cf][l15] = q; }
  }
  __syncthreads();
  if (tid < 64){
    int cf = tid >> 4, c = tid & 15;
    float s = ssum[0][cf][c]+ssum[1][cf][c]+ssum[2][cf][c]+ssum[3][cf][c];
    float q = ssq[0][cf][c]+ssq[1][cf][c]+ssq[2][cf][c]+ssq[3][cf][c];
    part[(size_t)blk*128 + tid*2]     = s;
    part[(size_t)blk*128 + tid*2 + 1] = q;
  }
}

// ---------------- BN3: read bf16 out_pre, write fp32 d_out ------------------
__global__ __launch_bounds__(256) void k_bn3(const bf16* __restrict__ pre,
    float* __restrict__ out,
    const float* __restrict__ sc, const float* __restrict__ sh){
  size_t total8 = (size_t)BB*CC*NN*TT/8;
  for (size_t i8 = (size_t)blockIdx.x*256 + threadIdx.x; i8 < total8;
       i8 += (size_t)gridDim.x*256){
    bf16x8 v = reinterpret_cast<const bf16x8*>(pre)[i8];
    int o = (int)(i8 >> 12) & 63;                  // n*t = 32768 per (b,o)
    float a = sc[o], bsh = sh[o];
    float4 r0, r1;
    r0.x = (float)v[0]*a + bsh; r0.y = (float)v[1]*a + bsh;
    r0.z = (float)v[2]*a + bsh; r0.w = (float)v[3]*a + bsh;
    r1.x = (float)v[4]*a + bsh; r1.y = (float)v[5]*a + bsh;
    r1.z = (float)v[6]*a + bsh; r1.w = (float)v[7]*a + bsh;
    reinterpret_cast<float4*>(out)[i8*2]     = r0;
    reinterpret_cast<float4*>(out)[i8*2 + 1] = r1;
  }
}

extern "C" void kernel_launch(void* const* d_in, const int* in_sizes, int n_in,
                              void* d_out, int out_size, void* d_ws, size_t ws_size,
                              hipStream_t stream){
  (void)in_sizes; (void)n_in; (void)out_size; (void)ws_size;
  const float* x   = (const float*)d_in[0];
  const float* adj = (const float*)d_in[1];
  const float* cw  = (const float*)d_in[2];
  const float* cb  = (const float*)d_in[3];
  const float* w1  = (const float*)d_in[4];
  // d_in[5] = b1 (cancels in BN1)
  const float* g1  = (const float*)d_in[6];
  const float* be1 = (const float*)d_in[7];
  const float* w2  = (const float*)d_in[8];
  // d_in[9] = b2 (cancels in BN2)
  const float* g2  = (const float*)d_in[10];
  const float* be2 = (const float*)d_in[11];
  const float* gw  = (const float*)d_in[12];
  const float* gb  = (const float*)d_in[13];
  const float* rw  = (const float*)d_in[14];
  // d_in[15] = res_b (cancels in BN3)
  const float* g3  = (const float*)d_in[16];
  const float* be3 = (const float*)d_in[17];
  float* out = (float*)d_out;

  char* ws = (char*)d_ws;
  size_t off = 0;
  auto alloc = [&](size_t bytes)->char*{
    char* p = ws + off; off += (bytes + 255) & ~(size_t)255; return p;
  };
  bf16* xlb  = (bf16*)alloc((size_t)PP*64*2);        // 67MB channel-last x
  bf16* xmt  = (bf16*)alloc((size_t)PP*64*2);        // 67MB; reused as out_pre
  bf16* t1   = (bf16*)alloc((size_t)PP*64*2);        // 67MB; reused as spm
  bf16* t2   = (bf16*)alloc((size_t)PP*64*2);        // 67MB
  bf16* spm  = t1;                                   // alias (t1 dead after conv2)
  bf16* pre  = xmt;                                  // alias (xmt dead after gemm1)
  bf16* adjb = (bf16*)alloc((size_t)KCH*512*512*2);
  bf16* w1p  = (bf16*)alloc(6*2048*2);
  bf16* w2p  = (bf16*)alloc(6*2048*2);
  bf16* cp   = (bf16*)alloc(6*2048*2);
  bf16* gp   = (bf16*)alloc(4*2048*2);
  bf16* rp   = (bf16*)alloc(2*2048*2);
  float* part = (float*)alloc((size_t)8192*128*4);   // shared partials (sequential)
  float* s1sc = (float*)alloc(256); float* s1sh = (float*)alloc(256);
  float* s2sc = (float*)alloc(256); float* s2sh = (float*)alloc(256);
  float* s3sc = (float*)alloc(256); float* s3sh = (float*)alloc(256);

  k_adjT <<<dim3(3072), dim3(256), 0, stream>>>(adj, adjb);
  k_wprep<<<dim3(1),    dim3(256), 0, stream>>>(w1, w2, cw, gw, rw, w1p, w2p, cp, gp, rp);
  k_xlb  <<<dim3(8192), dim3(256), 0, stream>>>(x, xlb);
  k_xmt  <<<dim3(1024), dim3(256), 0, stream>>>(x, xmt);

  k_conv <<<dim3(8192), dim3(256), 0, stream>>>(xlb, w1p, t1, part, nullptr, nullptr);
  k_stats<<<dim3(64),   dim3(256), 0, stream>>>(part, 8192, g1, be1, s1sc, s1sh);
  k_conv <<<dim3(8192), dim3(256), 0, stream>>>(t1, w2p, t2, part, s1sc, s1sh);
  k_stats<<<dim3(64),   dim3(256), 0, stream>>>(part, 8192, g2, be2, s2sc, s2sh);

  k_gemm1<<<dim3(2048), dim3(256), 0, stream>>>(xmt, adjb, cp, cb, spm);

  k_fusion<<<dim3(8192), dim3(256), 0, stream>>>(spm, t2, xlb, gp, rp,
                                                 s2sc, s2sh, gb, pre, part);
  k_stats<<<dim3(64),   dim3(256), 0, stream>>>(part, 8192, g3, be3, s3sc, s3sh);
  k_bn3  <<<dim3(2048), dim3(256), 0, stream>>>(pre, out, s3sc, s3sh);
}

// Round 7
// 609.174 us; speedup vs baseline: 1.1077x; 1.0771x over previous
//
#include <hip/hip_runtime.h>
#include <hip/hip_bf16.h>
#include <cstdint>

// Problem dims
#define BB 16
#define CC 64
#define NN 512
#define TT 64
#define KCH 3
#define PP (BB*NN*TT)      // 524288 points
#define EPSB 1e-5f

typedef __bf16 bf16;
typedef __bf16 bf16x8 __attribute__((ext_vector_type(8)));
typedef __bf16 bf16x4 __attribute__((ext_vector_type(4)));
typedef float  f32x4  __attribute__((ext_vector_type(4)));

#define MFMA16(A,Bv,Cv) __builtin_amdgcn_mfma_f32_16x16x32_bf16((A),(Bv),(Cv),0,0,0)

__device__ __forceinline__ void gload_lds16(const bf16* g, bf16* l){
  __builtin_amdgcn_global_load_lds(
      (const __attribute__((address_space(1))) void*)g,
      (__attribute__((address_space(3))) void*)l, 16, 0, 0);
}

// ---------------- prep: adjb[k][n][m] = bf16(adj[k][m][n]) ----------------
__global__ __launch_bounds__(256) void k_adjT(const float* __restrict__ adj,
                                              bf16* __restrict__ adjb){
  int idx = blockIdx.x*256 + threadIdx.x;          // over 3*512*512, exact grid
  int m = idx & 511, n = (idx >> 9) & 511, k = idx >> 18;
  adjb[idx] = (bf16)adj[((size_t)(k*512 + m))*512 + n];
}

// ---------------- prep: weights into MFMA B-fragment layout ----------------
__global__ __launch_bounds__(256) void k_wprep(const float* __restrict__ w1,
    const float* __restrict__ w2, const float* __restrict__ cw,
    const float* __restrict__ gw, const float* __restrict__ rw,
    bf16* __restrict__ w1p, bf16* __restrict__ w2p, bf16* __restrict__ cp,
    bf16* __restrict__ gp, bf16* __restrict__ rp){
  int tid = threadIdx.x;
  for (int e = tid; e < 6*2048; e += 256){          // K=192 groups (conv & cheb)
    int j = e&7, lane = (e>>3)&63, cf = (e>>9)&3, ks = e>>11;
    int k = ks*32 + (lane>>4)*8 + j, col = cf*16 + (lane&15);
    int kk = k >> 6, i = k & 63;                    // (dt|chebk, channel)
    w1p[e] = (bf16)w1[(col*64 + i)*3 + kk];         // w1[o][i][dt]
    w2p[e] = (bf16)w2[(col*64 + i)*3 + kk];
    cp[e]  = (bf16)cw[((size_t)kk*64 + i)*64 + col];// cheb_w[k][i][o]
  }
  for (int e = tid; e < 4*2048; e += 256){          // K=128 (gate)
    int j = e&7, lane = (e>>3)&63, cf = (e>>9)&3, ks = e>>11;
    int k = ks*32 + (lane>>4)*8 + j, col = cf*16 + (lane&15);
    gp[e] = (bf16)gw[col*128 + k];                  // gate_w[g][c]
  }
  for (int e = tid; e < 2*2048; e += 256){          // K=64 (res)
    int j = e&7, lane = (e>>3)&63, cf = (e>>9)&3, ks = e>>11;
    int k = ks*32 + (lane>>4)*8 + j, col = cf*16 + (lane&15);
    rp[e] = (bf16)rw[col*64 + k];                   // res_w[o][i]
  }
}

// ---------------- prep: xlb[b][n][t][i] = bf16(x[b][i][n][t]) --------------
__global__ __launch_bounds__(256) void k_xlb(const float* __restrict__ x,
                                             bf16* __restrict__ xlb){
  __shared__ float tile[64][65];
  int bn = blockIdx.x; int b = bn >> 9, n = bn & 511;
  int tid = threadIdx.x;
  const float* xp = x + ((size_t)(b*64)*512 + n)*64;   // x[b][0][n][0]
  for (int p = 0; p < 4; ++p){
    int q = p*256 + tid;                  // quad id 0..1023
    int i = q >> 4, tc = (q & 15)*4;
    float4 v = *reinterpret_cast<const float4*>(xp + (size_t)i*512*64 + tc);
    tile[i][tc+0] = v.x; tile[i][tc+1] = v.y; tile[i][tc+2] = v.z; tile[i][tc+3] = v.w;
  }
  __syncthreads();
  bf16* op = xlb + (size_t)bn*4096;
  for (int p = 0; p < 2; ++p){
    int v8 = p*256 + tid;                 // 0..511
    int t = v8 >> 3, ic = (v8 & 7)*8;
    bf16x8 o;
    #pragma unroll
    for (int e = 0; e < 8; ++e) o[e] = (bf16)tile[ic+e][t];
    *reinterpret_cast<bf16x8*>(op + t*64 + ic) = o;
  }
}

// ---------------- prep: xmt[b][t][i][m] = bf16(x[b][i][m][t]) --------------
__global__ __launch_bounds__(256) void k_xmt(const float* __restrict__ x,
                                             bf16* __restrict__ xmt){
  __shared__ bf16 T[32768];               // 64KB: [im(512)][slot(16)][4]
  int bid = blockIdx.x;
  int b = bid >> 6, i0 = ((bid >> 3) & 7)*8, m0 = (bid & 7)*64;
  int tid = threadIdx.x;
  #pragma unroll 4
  for (int it = 0; it < 32; ++it){
    int flat = it*256 + tid;              // [0,8192)
    int t4 = flat & 15, m = (flat >> 4) & 63, i = flat >> 10;
    float4 v = *reinterpret_cast<const float4*>(
        x + ((size_t)((b*64 + i0 + i)*512) + (m0 + m))*64 + t4*4);
    int im = i*64 + m;
    int slot = t4 ^ ((m ^ i) & 15);
    bf16x4 pk; pk[0] = (bf16)v.x; pk[1] = (bf16)v.y; pk[2] = (bf16)v.z; pk[3] = (bf16)v.w;
    *reinterpret_cast<bf16x4*>(&T[im*64 + slot*4]) = pk;
  }
  __syncthreads();
  #pragma unroll 4
  for (int it = 0; it < 16; ++it){
    int flat = it*256 + tid;              // [0,4096)
    int mc = flat & 7, i = (flat >> 3) & 7, t = flat >> 6;
    bf16x8 o;
    #pragma unroll
    for (int e = 0; e < 8; ++e){
      int m = mc*8 + e;
      int slot = (t >> 2) ^ ((m ^ i) & 15);
      o[e] = T[(i*64 + m)*64 + slot*4 + (t & 3)];
    }
    *reinterpret_cast<bf16x8*>(
        &xmt[((size_t)((b*64 + t)*64) + i0 + i)*512 + m0 + mc*8]) = o;
  }
}

// ---------------- temporal conv (1x3) as tall GEMM; optional BN+relu on load
__global__ __launch_bounds__(256,4) void k_conv(const bf16* __restrict__ in,
    const bf16* __restrict__ wp, bf16* __restrict__ outp, float* __restrict__ part,
    const float* __restrict__ sc, const float* __restrict__ sh){
  int tid = threadIdx.x, w = tid >> 6, l = tid & 63, l15 = l & 15, lg = l >> 4;
  int blk = blockIdx.x;
  size_t rowbase = (size_t)blk * 64;
  const bf16* xr = in + rowbase * 64;
  int t = w*16 + l15;
  f32x4 acc[4] = {};
  #pragma unroll
  for (int ks = 0; ks < 6; ++ks){
    int dt = ks >> 1, kh = ks & 1;
    int ts = t + dt - 1;
    bf16x8 a = {};
    if (ts >= 0 && ts < 64){
      a = *reinterpret_cast<const bf16x8*>(xr + ts*64 + kh*32 + lg*8);
      if (sc){                                  // BN1+relu applied on load
        int i0 = kh*32 + lg*8;
        #pragma unroll
        for (int e = 0; e < 8; ++e){
          float f = (float)a[e]*sc[i0+e] + sh[i0+e];
          a[e] = (bf16)fmaxf(f, 0.f);
        }
      }
    }
    #pragma unroll
    for (int cf = 0; cf < 4; ++cf){
      bf16x8 bfr = *reinterpret_cast<const bf16x8*>(wp + ((ks*4 + cf)*64 + l)*8);
      acc[cf] = MFMA16(a, bfr, acc[cf]);
    }
  }
  __shared__ float ssum[4][4][16], ssq[4][4][16];
  #pragma unroll
  for (int cf = 0; cf < 4; ++cf){
    int o = cf*16 + l15;
    float s = 0.f, q = 0.f;
    #pragma unroll
    for (int r = 0; r < 4; ++r){
      float vv = acc[cf][r];
      int to = w*16 + lg*4 + r;
      outp[(rowbase + to)*64 + o] = (bf16)vv;
      s += vv; q += vv*vv;
    }
    s += __shfl_xor(s, 16); s += __shfl_xor(s, 32);
    q += __shfl_xor(q, 16); q += __shfl_xor(q, 32);
    if (lg == 0){ ssum[w][cf][l15] = s; ssq[w][cf][l15] = q; }
  }
  __syncthreads();
  if (tid < 64){
    int cf = tid >> 4, c = tid & 15;
    float s = ssum[0][cf][c]+ssum[1][cf][c]+ssum[2][cf][c]+ssum[3][cf][c];
    float q = ssq[0][cf][c]+ssq[1][cf][c]+ssq[2][cf][c]+ssq[3][cf][c];
    part[(size_t)blk*128 + tid*2]     = s;
    part[(size_t)blk*128 + tid*2 + 1] = q;
  }
}

// ---------------- BN stats finalize: partials -> scale/shift ----------------
__global__ __launch_bounds__(256) void k_stats(const float* __restrict__ part, int nb,
    const float* __restrict__ g, const float* __restrict__ be,
    float* __restrict__ sc, float* __restrict__ sh){
  int c = blockIdx.x, tid = threadIdx.x;
  float s = 0.f, q = 0.f;
  for (int i = tid; i < nb; i += 256){
    s += part[(size_t)i*128 + c*2];
    q += part[(size_t)i*128 + c*2 + 1];
  }
  __shared__ float rs[256], rq[256];
  rs[tid] = s; rq[tid] = q; __syncthreads();
  for (int st = 128; st > 0; st >>= 1){
    if (tid < st){ rs[tid] += rs[tid+st]; rq[tid] += rq[tid+st]; }
    __syncthreads();
  }
  if (tid == 0){
    float cnt = (float)PP;
    float mean = rs[0]/cnt, var = rq[0]/cnt - mean*mean;
    float r = rsqrtf(var + EPSB);
    sc[c] = g[c]*r;
    sh[c] = be[c] - mean*g[c]*r;
  }
}

// ---------------- fused GEMM1+cheb: spm[(b,n,t)][o] ------------------------
// v6: 512 threads (8 waves), 128x128 tile. Per-thread acc halved vs 4-wave
// version -> fits 128 VGPR cap at __launch_bounds__(512,4): 16 waves/CU,
// no spills. 48KB LDS (2-buf 32KB + 16KB half-VT). Full XOR swizzle
// (c ^ (r&3) ^ ((r>>2)&3)) -> 2-way (free) LDS reads, 64B-coalesced global.
// Counted vmcnt(2) + raw barriers; lgkm-only fences in cheb phases.
__global__ __launch_bounds__(512,4) void k_gemm1(const bf16* __restrict__ xmt,
    const bf16* __restrict__ adjb, const bf16* __restrict__ cp,
    const float* __restrict__ cb, bf16* __restrict__ spm){
  __shared__ bf16 As[2][4096];          // [buf][row128][chunk4 swz][8]
  __shared__ bf16 Bs[2][4096];
  __shared__ bf16 VT[64*128];           // 16KB half-tile; reused as SP[128][64]

  int tid = threadIdx.x, w = tid >> 6, l = tid & 63, l15 = l & 15, lg = l >> 4;
  int wr = w >> 2, wc = w & 3;          // j-half, n-quarter

  // bijective XCD swizzle over 2048 blocks; nt innermost (A-panel shared by 4)
  int orig = blockIdx.x;
  int wg = (orig & 7) * 256 + (orig >> 3);
  int jt = wg >> 2, nt = wg & 3;
  int J0 = jt*128, N0 = nt*128;

  const bf16* aglob = xmt + (size_t)J0*512;
  const bf16* bbase = adjb + (size_t)N0*512;

  // staging: thread -> (row sr, chunk sc); global chunk XOR-permuted
  int sr = tid >> 2, sc = tid & 3;
  int scg = sc ^ (sr & 3) ^ ((sr >> 2) & 3);
  size_t soff = (size_t)sr*512 + scg*8;

  auto stage = [&](int t){              // 2 gload instrs per wave (vmcnt +2)
    int buf = t & 1;
    const bf16* bg = bbase + (size_t)(t >> 4)*(512*512);
    int m0 = (t & 15)*32;
    gload_lds16(aglob + soff + m0, &As[buf][tid*8]);
    gload_lds16(bg    + soff + m0, &Bs[buf][tid*8]);
  };

  // LDS read offsets (elements), loop-invariant
  int aoff[4], boff[2];
  #pragma unroll
  for (int rf = 0; rf < 4; ++rf){
    int row = wr*64 + rf*16 + l15;
    aoff[rf] = row*32 + ((lg ^ (row & 3) ^ ((row >> 2) & 3))*8);
  }
  #pragma unroll
  for (int cf = 0; cf < 2; ++cf){
    int row = wc*32 + cf*16 + l15;
    boff[cf] = row*32 + ((lg ^ (row & 3) ^ ((row >> 2) & 3))*8);
  }

  f32x4 acc[4][2] = {};
  f32x4 acc2[2][4] = {};

  stage(0);
  for (int t = 0; t < 48; ++t){
    if (t < 47){
      stage(t+1);
      asm volatile("s_waitcnt vmcnt(2)" ::: "memory");   // tile t landed
    } else {
      asm volatile("s_waitcnt vmcnt(0)" ::: "memory");
    }
    __builtin_amdgcn_s_barrier();
    __builtin_amdgcn_sched_barrier(0);

    int buf = t & 1;
    bf16x8 a[4], bb[2];
    #pragma unroll
    for (int rf = 0; rf < 4; ++rf)
      a[rf] = *reinterpret_cast<const bf16x8*>(&As[buf][aoff[rf]]);
    #pragma unroll
    for (int cf = 0; cf < 2; ++cf)
      bb[cf] = *reinterpret_cast<const bf16x8*>(&Bs[buf][boff[cf]]);
    #pragma unroll
    for (int rf = 0; rf < 4; ++rf)
      #pragma unroll
      for (int cf = 0; cf < 2; ++cf)
        acc[rf][cf] = MFMA16(a[rf], bb[cf], acc[rf][cf]);

    // seal this buffer's reads before next iter's stage overwrites it
    asm volatile("s_waitcnt lgkmcnt(0)" ::: "memory");
    __builtin_amdgcn_sched_barrier(0);
    __builtin_amdgcn_s_barrier();

    if ((t & 15) == 15){
      int kk = t >> 4;
      #pragma unroll
      for (int h = 0; h < 2; ++h){
        // dump half h (n in [h*64,h*64+64)): waves with wc in {2h,2h+1}
        if ((wc >> 1) == h){
          #pragma unroll
          for (int rf = 0; rf < 4; ++rf){
            int jb = wr*8 + rf*2 + (lg >> 1);   // j0 = wr*64+rf*16+lg*4
            #pragma unroll
            for (int cf = 0; cf < 2; ++cf){
              int nh = (wc & 1)*32 + cf*16 + l15;
              bf16x4 pk;
              #pragma unroll
              for (int r = 0; r < 4; ++r) pk[r] = (bf16)acc[rf][cf][r];
              *reinterpret_cast<bf16x4*>(
                  &VT[nh*128 + ((jb ^ (nh & 15)) << 3) + ((lg & 1) << 2)]) = pk;
            }
          }
        }
        asm volatile("s_waitcnt lgkmcnt(0)" ::: "memory");
        __builtin_amdgcn_sched_barrier(0);
        __builtin_amdgcn_s_barrier();

        // contract: all 8 waves; wave -> (t_out = w>>2, n-16-group = w&3)
        #pragma unroll
        for (int ks2 = 0; ks2 < 2; ++ks2){
          bf16x8 bc[4];
          #pragma unroll
          for (int cf = 0; cf < 4; ++cf)
            bc[cf] = *reinterpret_cast<const bf16x8*>(
                cp + (((kk*2 + ks2)*4 + cf)*64 + l)*8);
          int nh = (w & 3)*16 + l15;
          int jb = (w >> 2)*8 + ks2*4 + lg;
          bf16x8 a2 = *reinterpret_cast<const bf16x8*>(
              &VT[nh*128 + ((jb ^ (nh & 15)) << 3)]);
          #pragma unroll
          for (int cf = 0; cf < 4; ++cf)
            acc2[h][cf] = MFMA16(a2, bc[cf], acc2[h][cf]);
        }
        asm volatile("s_waitcnt lgkmcnt(0)" ::: "memory");
        __builtin_amdgcn_sched_barrier(0);
        __builtin_amdgcn_s_barrier();
      }
      // reset main accumulator for next kk
      #pragma unroll
      for (int rf = 0; rf < 4; ++rf)
        #pragma unroll
        for (int cf = 0; cf < 2; ++cf)
          acc[rf][cf] = (f32x4){0.f, 0.f, 0.f, 0.f};
    }
  }

  // epilogue in two t-halves through SP=VT (16KB = [n:128][o:64])
  bf16* SP = VT;
  float cbv[4];
  #pragma unroll
  for (int cf = 0; cf < 4; ++cf) cbv[cf] = cb[cf*16 + l15];
  int b = jt >> 5, t0 = (jt & 31)*2;
  #pragma unroll
  for (int hr = 0; hr < 2; ++hr){
    if ((w >> 2) == hr){                  // waves owning t_out == hr
      #pragma unroll
      for (int h = 0; h < 2; ++h){
        int rowb = h*64 + (w & 3)*16 + lg*4;     // n within [0,128)
        #pragma unroll
        for (int cf = 0; cf < 4; ++cf){
          int o = cf*16 + l15;
          #pragma unroll
          for (int r = 0; r < 4; ++r)
            SP[(rowb + r)*64 + o] = (bf16)(acc2[h][cf][r] + cbv[cf]);
        }
      }
    }
    __syncthreads();
    #pragma unroll
    for (int q = 0; q < 2; ++q){
      int flat = q*512 + tid;             // 1024 chunks of 8 elems
      int n = flat >> 3, oc = (flat & 7)*8;
      bf16x8 vv = *reinterpret_cast<const bf16x8*>(&SP[n*64 + oc]);
      *reinterpret_cast<bf16x8*>(
          &spm[(((size_t)b*512 + N0 + n)*64 + (t0 + hr))*64 + oc]) = vv;
    }
    __syncthreads();
  }
}

// ---------------- fusion: gate/res MFMA + combine; writes bf16 out_pre -----
__global__ __launch_bounds__(256,4) void k_fusion(const bf16* __restrict__ spm,
    const bf16* __restrict__ t2, const bf16* __restrict__ xlb,
    const bf16* __restrict__ gp, const bf16* __restrict__ rp,
    const float* __restrict__ sc2, const float* __restrict__ sh2,
    const float* __restrict__ gateb, bf16* __restrict__ pre,
    float* __restrict__ part){
  int tid = threadIdx.x, w = tid >> 6, l = tid & 63, l15 = l & 15, lg = l >> 4;
  int blk = blockIdx.x;
  int b = blk >> 9, n = blk & 511;
  size_t rowbase = (size_t)blk * 64;
  int t = w*16 + l15;
  f32x4 ag[4] = {}, ar[4] = {};
  #pragma unroll
  for (int ks = 0; ks < 4; ++ks){                 // gate: K=128 = [spatial|t2bn]
    bf16x8 a;
    if (ks < 2){
      a = *reinterpret_cast<const bf16x8*>(spm + (rowbase + t)*64 + ks*32 + lg*8);
    } else {
      int i0 = (ks-2)*32 + lg*8;
      bf16x8 raw = *reinterpret_cast<const bf16x8*>(t2 + (rowbase + t)*64 + i0);
      #pragma unroll
      for (int e = 0; e < 8; ++e){
        float f = (float)raw[e]*sc2[i0+e] + sh2[i0+e];
        a[e] = (bf16)fmaxf(f, 0.f);
      }
    }
    #pragma unroll
    for (int cf = 0; cf < 4; ++cf){
      bf16x8 bfr = *reinterpret_cast<const bf16x8*>(gp + ((ks*4 + cf)*64 + l)*8);
      ag[cf] = MFMA16(a, bfr, ag[cf]);
    }
  }
  #pragma unroll
  for (int ks = 0; ks < 2; ++ks){                 // res: K=64 on x
    bf16x8 a = *reinterpret_cast<const bf16x8*>(xlb + (rowbase + t)*64 + ks*32 + lg*8);
    #pragma unroll
    for (int cf = 0; cf < 4; ++cf){
      bf16x8 bfr = *reinterpret_cast<const bf16x8*>(rp + ((ks*4 + cf)*64 + l)*8);
      ar[cf] = MFMA16(a, bfr, ar[cf]);
    }
  }
  __shared__ float ssum[4][4][16], ssq[4][4][16];
  int tb = w*16 + lg*4;
  #pragma unroll
  for (int cf = 0; cf < 4; ++cf){
    int o = cf*16 + l15;
    float gb = gateb[o], sco = sc2[o], sho = sh2[o];
    float s = 0.f, q = 0.f;
    bf16x4 ov;
    #pragma unroll
    for (int r = 0; r < 4; ++r){
      size_t row = rowbase + tb + r;
      float z = ag[cf][r] + gb;
      float g = 1.f/(1.f + __expf(-z));
      float spv = (float)spm[row*64 + o];
      float tv  = (float)t2[row*64 + o];
      tv = fmaxf(tv*sco + sho, 0.f);
      float val = g*spv + (1.f - g)*tv + ar[cf][r];
      ov[r] = (bf16)val;
      s += val; q += val*val;
    }
    *reinterpret_cast<bf16x4*>(pre + (((size_t)b*64 + o)*512 + n)*64 + tb) = ov;
    s += __shfl_xor(s, 16); s += __shfl_xor(s, 32);
    q += __shfl_xor(q, 16); q += __shfl_xor(q, 32);
    if (lg == 0){ ssum[w][cf][l15] = s; ssq[w][cf][l15] = q; }
  }
  __syncthreads();
  if (tid < 64){
    int cf = tid >> 4, c = tid & 15;
    float s = ssum[0][cf][c]+ssum[1][cf][c]+ssum[2][cf][c]+ssum[3][cf][c];
    float q = ssq[0][cf][c]+ssq[1][cf][c]+ssq[2][cf][c]+ssq[3][cf][c];
    part[(size_t)blk*128 + tid*2]     = s;
    part[(size_t)blk*128 + tid*2 + 1] = q;
  }
}

// ---------------- BN3: read bf16 out_pre, write fp32 d_out ------------------
__global__ __launch_bounds__(256) void k_bn3(const bf16* __restrict__ pre,
    float* __restrict__ out,
    const float* __restrict__ sc, const float* __restrict__ sh){
  size_t total8 = (size_t)BB*CC*NN*TT/8;
  for (size_t i8 = (size_t)blockIdx.x*256 + threadIdx.x; i8 < total8;
       i8 += (size_t)gridDim.x*256){
    bf16x8 v = reinterpret_cast<const bf16x8*>(pre)[i8];
    int o = (int)(i8 >> 12) & 63;                  // n*t = 32768 per (b,o)
    float a = sc[o], bsh = sh[o];
    float4 r0, r1;
    r0.x = (float)v[0]*a + bsh; r0.y = (float)v[1]*a + bsh;
    r0.z = (float)v[2]*a + bsh; r0.w = (float)v[3]*a + bsh;
    r1.x = (float)v[4]*a + bsh; r1.y = (float)v[5]*a + bsh;
    r1.z = (float)v[6]*a + bsh; r1.w = (float)v[7]*a + bsh;
    reinterpret_cast<float4*>(out)[i8*2]     = r0;
    reinterpret_cast<float4*>(out)[i8*2 + 1] = r1;
  }
}

extern "C" void kernel_launch(void* const* d_in, const int* in_sizes, int n_in,
                              void* d_out, int out_size, void* d_ws, size_t ws_size,
                              hipStream_t stream){
  (void)in_sizes; (void)n_in; (void)out_size; (void)ws_size;
  const float* x   = (const float*)d_in[0];
  const float* adj = (const float*)d_in[1];
  const float* cw  = (const float*)d_in[2];
  const float* cb  = (const float*)d_in[3];
  const float* w1  = (const float*)d_in[4];
  // d_in[5] = b1 (cancels in BN1)
  const float* g1  = (const float*)d_in[6];
  const float* be1 = (const float*)d_in[7];
  const float* w2  = (const float*)d_in[8];
  // d_in[9] = b2 (cancels in BN2)
  const float* g2  = (const float*)d_in[10];
  const float* be2 = (const float*)d_in[11];
  const float* gw  = (const float*)d_in[12];
  const float* gb  = (const float*)d_in[13];
  const float* rw  = (const float*)d_in[14];
  // d_in[15] = res_b (cancels in BN3)
  const float* g3  = (const float*)d_in[16];
  const float* be3 = (const float*)d_in[17];
  float* out = (float*)d_out;

  char* ws = (char*)d_ws;
  size_t off = 0;
  auto alloc = [&](size_t bytes)->char*{
    char* p = ws + off; off += (bytes + 255) & ~(size_t)255; return p;
  };
  bf16* xlb  = (bf16*)alloc((size_t)PP*64*2);        // 67MB channel-last x
  bf16* xmt  = (bf16*)alloc((size_t)PP*64*2);        // 67MB; reused as out_pre
  bf16* t1   = (bf16*)alloc((size_t)PP*64*2);        // 67MB; reused as spm
  bf16* t2   = (bf16*)alloc((size_t)PP*64*2);        // 67MB
  bf16* spm  = t1;                                   // alias (t1 dead after conv2)
  bf16* pre  = xmt;                                  // alias (xmt dead after gemm1)
  bf16* adjb = (bf16*)alloc((size_t)KCH*512*512*2);
  bf16* w1p  = (bf16*)alloc(6*2048*2);
  bf16* w2p  = (bf16*)alloc(6*2048*2);
  bf16* cp   = (bf16*)alloc(6*2048*2);
  bf16* gp   = (bf16*)alloc(4*2048*2);
  bf16* rp   = (bf16*)alloc(2*2048*2);
  float* part = (float*)alloc((size_t)8192*128*4);   // shared partials (sequential)
  float* s1sc = (float*)alloc(256); float* s1sh = (float*)alloc(256);
  float* s2sc = (float*)alloc(256); float* s2sh = (float*)alloc(256);
  float* s3sc = (float*)alloc(256); float* s3sh = (float*)alloc(256);

  k_adjT <<<dim3(3072), dim3(256), 0, stream>>>(adj, adjb);
  k_wprep<<<dim3(1),    dim3(256), 0, stream>>>(w1, w2, cw, gw, rw, w1p, w2p, cp, gp, rp);
  k_xlb  <<<dim3(8192), dim3(256), 0, stream>>>(x, xlb);
  k_xmt  <<<dim3(1024), dim3(256), 0, stream>>>(x, xmt);

  k_conv <<<dim3(8192), dim3(256), 0, stream>>>(xlb, w1p, t1, part, nullptr, nullptr);
  k_stats<<<dim3(64),   dim3(256), 0, stream>>>(part, 8192, g1, be1, s1sc, s1sh);
  k_conv <<<dim3(8192), dim3(256), 0, stream>>>(t1, w2p, t2, part, s1sc, s1sh);
  k_stats<<<dim3(64),   dim3(256), 0, stream>>>(part, 8192, g2, be2, s2sc, s2sh);

  k_gemm1<<<dim3(2048), dim3(512), 0, stream>>>(xmt, adjb, cp, cb, spm);

  k_fusion<<<dim3(8192), dim3(256), 0, stream>>>(spm, t2, xlb, gp, rp,
                                                 s2sc, s2sh, gb, pre, part);
  k_stats<<<dim3(64),   dim3(256), 0, stream>>>(part, 8192, g3, be3, s3sc, s3sh);
  k_bn3  <<<dim3(2048), dim3(256), 0, stream>>>(pre, out, s3sc, s3sh);
}

// Round 8
// 548.374 us; speedup vs baseline: 1.2306x; 1.1109x over previous
//
#include <hip/hip_runtime.h>
#include <hip/hip_bf16.h>
#include <cstdint>

// Problem dims
#define BB 16
#define CC 64
#define NN 512
#define TT 64
#define KCH 3
#define PP (BB*NN*TT)      // 524288 points
#define EPSB 1e-5f

typedef __bf16 bf16;
typedef __bf16 bf16x8 __attribute__((ext_vector_type(8)));
typedef __bf16 bf16x4 __attribute__((ext_vector_type(4)));
typedef float  f32x4  __attribute__((ext_vector_type(4)));

#define MFMA16(A,Bv,Cv) __builtin_amdgcn_mfma_f32_16x16x32_bf16((A),(Bv),(Cv),0,0,0)

__device__ __forceinline__ void gload_lds16(const bf16* g, bf16* l){
  __builtin_amdgcn_global_load_lds(
      (const __attribute__((address_space(1))) void*)g,
      (__attribute__((address_space(3))) void*)l, 16, 0, 0);
}

// ---------------- prep (merged): adjb transpose + weight fragment prep -----
// blocks [0,3072): adjb[k][n][m] = bf16(adj[k][m][n])
// blocks [3072,3168): weight prep spread over 96 blocks (was 1-block serial)
__global__ __launch_bounds__(256) void k_prep(const float* __restrict__ adj,
    const float* __restrict__ w1, const float* __restrict__ w2,
    const float* __restrict__ cw, const float* __restrict__ gw,
    const float* __restrict__ rw, bf16* __restrict__ adjb,
    bf16* __restrict__ w1p, bf16* __restrict__ w2p, bf16* __restrict__ cp,
    bf16* __restrict__ gp, bf16* __restrict__ rp){
  int blk = blockIdx.x, tid = threadIdx.x;
  if (blk < 3072){
    int idx = blk*256 + tid;
    int m = idx & 511, n = (idx >> 9) & 511, k = idx >> 18;
    adjb[idx] = (bf16)adj[((size_t)(k*512 + m))*512 + n];
    return;
  }
  int e0 = (blk - 3072)*256 + tid;                  // [0, 24576)
  if (e0 < 12288){                                  // K=192 groups (conv & cheb)
    int e = e0;
    int j = e&7, lane = (e>>3)&63, cf = (e>>9)&3, ks = e>>11;
    int k = ks*32 + (lane>>4)*8 + j, col = cf*16 + (lane&15);
    int kk = k >> 6, i = k & 63;
    w1p[e] = (bf16)w1[(col*64 + i)*3 + kk];
    w2p[e] = (bf16)w2[(col*64 + i)*3 + kk];
    cp[e]  = (bf16)cw[((size_t)kk*64 + i)*64 + col];
  } else if (e0 < 20480){                           // K=128 (gate)
    int e = e0 - 12288;
    int j = e&7, lane = (e>>3)&63, cf = (e>>9)&3, ks = e>>11;
    int k = ks*32 + (lane>>4)*8 + j, col = cf*16 + (lane&15);
    gp[e] = (bf16)gw[col*128 + k];
  } else {                                          // K=64 (res)
    int e = e0 - 20480;
    int j = e&7, lane = (e>>3)&63, cf = (e>>9)&3, ks = e>>11;
    int k = ks*32 + (lane>>4)*8 + j, col = cf*16 + (lane&15);
    rp[e] = (bf16)rw[col*64 + k];
  }
}

// ---------------- fused x prep: one read of x -> xlb AND xmt ----------------
// Tile: b fixed, i:8, n:64, t:64. Reads full 256B t-rows (coalesced).
// LDS T[i][n][slot16][4] bf16, slot = t4 ^ ((n + 2i)&15):
//   writes conflict-free; both emission patterns <=2-way.
// xlb[b][n][t][i0+0..7]  (16B stores, 128B stride over t)
// xmt[b][t][i0+i][m=n0+0..63] (16B stores contiguous in m)
__global__ __launch_bounds__(256) void k_xprep(const float* __restrict__ x,
    bf16* __restrict__ xlb, bf16* __restrict__ xmt){
  __shared__ bf16 T[32768];               // 64KB
  int bid = blockIdx.x;
  int b = bid >> 6, i0 = ((bid >> 3) & 7)*8, n0 = (bid & 7)*64;
  int tid = threadIdx.x;
  #pragma unroll 4
  for (int it = 0; it < 32; ++it){
    int flat = it*256 + tid;              // [0,8192)
    int t4 = flat & 15, n = (flat >> 4) & 63, i = flat >> 10;
    float4 v = *reinterpret_cast<const float4*>(
        x + ((size_t)((b*64 + i0 + i)*512) + (n0 + n))*64 + t4*4);
    int s = t4 ^ ((n + 2*i) & 15);
    bf16x4 pk; pk[0]=(bf16)v.x; pk[1]=(bf16)v.y; pk[2]=(bf16)v.z; pk[3]=(bf16)v.w;
    *reinterpret_cast<bf16x4*>(&T[(i*64 + n)*64 + s*4]) = pk;
  }
  __syncthreads();
  // xmt emission
  #pragma unroll 4
  for (int it = 0; it < 16; ++it){
    int flat = it*256 + tid;              // [0,4096)
    int mc = flat & 7, i = (flat >> 3) & 7, t = flat >> 6;
    bf16x8 o;
    #pragma unroll
    for (int e = 0; e < 8; ++e){
      int m = mc*8 + e;
      int s = (t >> 2) ^ ((m + 2*i) & 15);
      o[e] = T[(i*64 + m)*64 + s*4 + (t & 3)];
    }
    *reinterpret_cast<bf16x8*>(
        &xmt[((size_t)((b*64 + t)*64) + i0 + i)*512 + n0 + mc*8]) = o;
  }
  // xlb emission
  #pragma unroll 4
  for (int it = 0; it < 16; ++it){
    int flat = it*256 + tid;              // [0,4096)
    int t = flat & 63, n = flat >> 6;
    bf16x8 o;
    #pragma unroll
    for (int e = 0; e < 8; ++e){
      int s = (t >> 2) ^ ((n + 2*e) & 15);
      o[e] = T[(e*64 + n)*64 + s*4 + (t & 3)];
    }
    *reinterpret_cast<bf16x8*>(
        &xlb[(((size_t)b*512 + n0 + n)*64 + t)*64 + i0]) = o;
  }
}

// ---------------- temporal conv (1x3) as tall GEMM; optional BN+relu on load
__global__ __launch_bounds__(256,4) void k_conv(const bf16* __restrict__ in,
    const bf16* __restrict__ wp, bf16* __restrict__ outp, float* __restrict__ part,
    const float* __restrict__ sc, const float* __restrict__ sh){
  int tid = threadIdx.x, w = tid >> 6, l = tid & 63, l15 = l & 15, lg = l >> 4;
  int blk = blockIdx.x;
  size_t rowbase = (size_t)blk * 64;
  const bf16* xr = in + rowbase * 64;
  int t = w*16 + l15;
  f32x4 acc[4] = {};
  #pragma unroll
  for (int ks = 0; ks < 6; ++ks){
    int dt = ks >> 1, kh = ks & 1;
    int ts = t + dt - 1;
    bf16x8 a = {};
    if (ts >= 0 && ts < 64){
      a = *reinterpret_cast<const bf16x8*>(xr + ts*64 + kh*32 + lg*8);
      if (sc){                                  // BN1+relu applied on load
        int i0 = kh*32 + lg*8;
        #pragma unroll
        for (int e = 0; e < 8; ++e){
          float f = (float)a[e]*sc[i0+e] + sh[i0+e];
          a[e] = (bf16)fmaxf(f, 0.f);
        }
      }
    }
    #pragma unroll
    for (int cf = 0; cf < 4; ++cf){
      bf16x8 bfr = *reinterpret_cast<const bf16x8*>(wp + ((ks*4 + cf)*64 + l)*8);
      acc[cf] = MFMA16(a, bfr, acc[cf]);
    }
  }
  __shared__ float ssum[4][4][16], ssq[4][4][16];
  #pragma unroll
  for (int cf = 0; cf < 4; ++cf){
    int o = cf*16 + l15;
    float s = 0.f, q = 0.f;
    #pragma unroll
    for (int r = 0; r < 4; ++r){
      float vv = acc[cf][r];
      int to = w*16 + lg*4 + r;
      outp[(rowbase + to)*64 + o] = (bf16)vv;
      s += vv; q += vv*vv;
    }
    s += __shfl_xor(s, 16); s += __shfl_xor(s, 32);
    q += __shfl_xor(q, 16); q += __shfl_xor(q, 32);
    if (lg == 0){ ssum[w][cf][l15] = s; ssq[w][cf][l15] = q; }
  }
  __syncthreads();
  if (tid < 64){
    int cf = tid >> 4, c = tid & 15;
    float s = ssum[0][cf][c]+ssum[1][cf][c]+ssum[2][cf][c]+ssum[3][cf][c];
    float q = ssq[0][cf][c]+ssq[1][cf][c]+ssq[2][cf][c]+ssq[3][cf][c];
    part[(size_t)blk*128 + tid*2]     = s;
    part[(size_t)blk*128 + tid*2 + 1] = q;
  }
}

// ---------------- BN stats finalize: partials -> scale/shift ----------------
__global__ __launch_bounds__(256) void k_stats(const float* __restrict__ part, int nb,
    const float* __restrict__ g, const float* __restrict__ be,
    float* __restrict__ sc, float* __restrict__ sh){
  int c = blockIdx.x, tid = threadIdx.x;
  float s = 0.f, q = 0.f;
  for (int i = tid; i < nb; i += 256){
    s += part[(size_t)i*128 + c*2];
    q += part[(size_t)i*128 + c*2 + 1];
  }
  __shared__ float rs[256], rq[256];
  rs[tid] = s; rq[tid] = q; __syncthreads();
  for (int st = 128; st > 0; st >>= 1){
    if (tid < st){ rs[tid] += rs[tid+st]; rq[tid] += rq[tid+st]; }
    __syncthreads();
  }
  if (tid == 0){
    float cnt = (float)PP;
    float mean = rs[0]/cnt, var = rq[0]/cnt - mean*mean;
    float r = rsqrtf(var + EPSB);
    sc[c] = g[c]*r;
    sh[c] = be[c] - mean*g[c]*r;
  }
}

// ---------------- fused GEMM1+cheb: spm[(b,n,t)][o] ------------------------
// v7: 8 waves, 128x128 tile, 3-buffer 2-deep prefetch (vmcnt(4) -> ~2 K-steps
// of latency tolerance), full 32KB VT (single cheb phase per kk, 2 barriers).
// 80KB LDS -> exactly 2 blocks/CU. Post-contraction barrier dropped (next VT
// write is >=16 barrier-sealed K-steps away).
__global__ __launch_bounds__(512,4) void k_gemm1(const bf16* __restrict__ xmt,
    const bf16* __restrict__ adjb, const bf16* __restrict__ cp,
    const float* __restrict__ cb, bf16* __restrict__ spm){
  __shared__ bf16 As[3][4096];          // [buf][row128][chunk4 swz][8]
  __shared__ bf16 Bs[3][4096];
  __shared__ bf16 VT[128*128];          // 32KB; VT[n][j] swz; reused SP[256][64]

  int tid = threadIdx.x, w = tid >> 6, l = tid & 63, l15 = l & 15, lg = l >> 4;
  int wr = w >> 2, wc = w & 3;          // j-half, n-quarter

  // bijective XCD swizzle over 2048 blocks; nt innermost (A-panel shared by 4)
  int orig = blockIdx.x;
  int wg = (orig & 7) * 256 + (orig >> 3);
  int jt = wg >> 2, nt = wg & 3;
  int J0 = jt*128, N0 = nt*128;

  const bf16* aglob = xmt + (size_t)J0*512;
  const bf16* bbase = adjb + (size_t)N0*512;

  // staging: thread -> (row sr, chunk sc); global chunk XOR-permuted
  int sr = tid >> 2, sc = tid & 3;
  int scg = sc ^ (sr & 3) ^ ((sr >> 2) & 3);
  size_t soff = (size_t)sr*512 + scg*8;

  auto stage = [&](int t){              // 2 gload instrs per wave (vmcnt +2)
    int buf = t % 3;
    const bf16* bg = bbase + (size_t)(t >> 4)*(512*512);
    int m0 = (t & 15)*32;
    gload_lds16(aglob + soff + m0, &As[buf][tid*8]);
    gload_lds16(bg    + soff + m0, &Bs[buf][tid*8]);
  };

  // LDS read offsets (elements), loop-invariant
  int aoff[4], boff[2];
  #pragma unroll
  for (int rf = 0; rf < 4; ++rf){
    int row = wr*64 + rf*16 + l15;
    aoff[rf] = row*32 + ((lg ^ (row & 3) ^ ((row >> 2) & 3))*8);
  }
  #pragma unroll
  for (int cf = 0; cf < 2; ++cf){
    int row = wc*32 + cf*16 + l15;
    boff[cf] = row*32 + ((lg ^ (row & 3) ^ ((row >> 2) & 3))*8);
  }

  f32x4 acc[4][2] = {};
  f32x4 acc2[2][4] = {};

  stage(0); stage(1);
  for (int t = 0; t < 48; ++t){
    if (t < 46){
      stage(t+2);
      asm volatile("s_waitcnt vmcnt(4)" ::: "memory");   // tile t landed
    } else if (t == 46){
      asm volatile("s_waitcnt vmcnt(2)" ::: "memory");
    } else {
      asm volatile("s_waitcnt vmcnt(0)" ::: "memory");
    }
    __builtin_amdgcn_s_barrier();
    __builtin_amdgcn_sched_barrier(0);

    int buf = t % 3;
    bf16x8 a[4], bb[2];
    #pragma unroll
    for (int rf = 0; rf < 4; ++rf)
      a[rf] = *reinterpret_cast<const bf16x8*>(&As[buf][aoff[rf]]);
    #pragma unroll
    for (int cf = 0; cf < 2; ++cf)
      bb[cf] = *reinterpret_cast<const bf16x8*>(&Bs[buf][boff[cf]]);
    #pragma unroll
    for (int rf = 0; rf < 4; ++rf)
      #pragma unroll
      for (int cf = 0; cf < 2; ++cf)
        acc[rf][cf] = MFMA16(a[rf], bb[cf], acc[rf][cf]);

    // seal this buffer's reads before a later stage overwrites it
    asm volatile("s_waitcnt lgkmcnt(0)" ::: "memory");
    __builtin_amdgcn_sched_barrier(0);
    __builtin_amdgcn_s_barrier();

    if ((t & 15) == 15){
      int kk = t >> 4;
      // full V-tile dump: wave owns j-rows wr*64.., n-cols wc*32..
      #pragma unroll
      for (int rf = 0; rf < 4; ++rf){
        int jb = wr*8 + rf*2 + (lg >> 1);         // j0 = wr*64+rf*16+lg*4
        #pragma unroll
        for (int cf = 0; cf < 2; ++cf){
          int nh = wc*32 + cf*16 + l15;           // n in [0,128)
          bf16x4 pk;
          #pragma unroll
          for (int r = 0; r < 4; ++r) pk[r] = (bf16)acc[rf][cf][r];
          *reinterpret_cast<bf16x4*>(
              &VT[nh*128 + ((jb ^ (nh & 15)) << 3) + ((lg & 1) << 2)]) = pk;
          acc[rf][cf] = (f32x4){0.f, 0.f, 0.f, 0.f};
        }
      }
      asm volatile("s_waitcnt lgkmcnt(0)" ::: "memory");
      __builtin_amdgcn_sched_barrier(0);
      __builtin_amdgcn_s_barrier();

      // cheb contraction, single phase: wave -> t_out = w>>2, n-grp = w&3
      #pragma unroll
      for (int ks2 = 0; ks2 < 2; ++ks2){
        bf16x8 bc[4];
        #pragma unroll
        for (int cf = 0; cf < 4; ++cf)
          bc[cf] = *reinterpret_cast<const bf16x8*>(
              cp + (((kk*2 + ks2)*4 + cf)*64 + l)*8);
        #pragma unroll
        for (int h = 0; h < 2; ++h){
          int nh = h*64 + (w & 3)*16 + l15;
          int jb = (w >> 2)*8 + ks2*4 + lg;
          bf16x8 a2 = *reinterpret_cast<const bf16x8*>(
              &VT[nh*128 + ((jb ^ (nh & 15)) << 3)]);
          #pragma unroll
          for (int cf = 0; cf < 4; ++cf)
            acc2[h][cf] = MFMA16(a2, bc[cf], acc2[h][cf]);
        }
      }
      // no trailing barrier: next VT write is 16 sealed K-steps away
    }
  }

  __syncthreads();                      // all contraction reads done before SP
  // epilogue: SP[row=(t_out*128+n)][o] = acc2 + cheb_b, then coalesced store
  bf16* SP = VT;
  float cbv[4];
  #pragma unroll
  for (int cf = 0; cf < 4; ++cf) cbv[cf] = cb[cf*16 + l15];
  int b = jt >> 5, t0 = (jt & 31)*2;
  #pragma unroll
  for (int h = 0; h < 2; ++h){
    int rowb = (w >> 2)*128 + h*64 + (w & 3)*16 + lg*4;
    #pragma unroll
    for (int cf = 0; cf < 4; ++cf){
      int o = cf*16 + l15;
      #pragma unroll
      for (int r = 0; r < 4; ++r)
        SP[(rowb + r)*64 + o] = (bf16)(acc2[h][cf][r] + cbv[cf]);
    }
  }
  __syncthreads();
  #pragma unroll
  for (int q = 0; q < 4; ++q){
    int flat = q*512 + tid;             // 2048 chunks of 8 elems
    int row = flat >> 3, oc = (flat & 7)*8;
    int tl = row >> 7, n = row & 127;
    bf16x8 vv = *reinterpret_cast<const bf16x8*>(&SP[row*64 + oc]);
    *reinterpret_cast<bf16x8*>(
        &spm[(((size_t)b*512 + N0 + n)*64 + (t0 + tl))*64 + oc]) = vv;
  }
}

// ---------------- fusion: gate/res MFMA + combine; writes bf16 out_pre -----
__global__ __launch_bounds__(256,4) void k_fusion(const bf16* __restrict__ spm,
    const bf16* __restrict__ t2, const bf16* __restrict__ xlb,
    const bf16* __restrict__ gp, const bf16* __restrict__ rp,
    const float* __restrict__ sc2, const float* __restrict__ sh2,
    const float* __restrict__ gateb, bf16* __restrict__ pre,
    float* __restrict__ part){
  int tid = threadIdx.x, w = tid >> 6, l = tid & 63, l15 = l & 15, lg = l >> 4;
  int blk = blockIdx.x;
  int b = blk >> 9, n = blk & 511;
  size_t rowbase = (size_t)blk * 64;
  int t = w*16 + l15;
  f32x4 ag[4] = {}, ar[4] = {};
  #pragma unroll
  for (int ks = 0; ks < 4; ++ks){                 // gate: K=128 = [spatial|t2bn]
    bf16x8 a;
    if (ks < 2){
      a = *reinterpret_cast<const bf16x8*>(spm + (rowbase + t)*64 + ks*32 + lg*8);
    } else {
      int i0 = (ks-2)*32 + lg*8;
      bf16x8 raw = *reinterpret_cast<const bf16x8*>(t2 + (rowbase + t)*64 + i0);
      #pragma unroll
      for (int e = 0; e < 8; ++e){
        float f = (float)raw[e]*sc2[i0+e] + sh2[i0+e];
        a[e] = (bf16)fmaxf(f, 0.f);
      }
    }
    #pragma unroll
    for (int cf = 0; cf < 4; ++cf){
      bf16x8 bfr = *reinterpret_cast<const bf16x8*>(gp + ((ks*4 + cf)*64 + l)*8);
      ag[cf] = MFMA16(a, bfr, ag[cf]);
    }
  }
  #pragma unroll
  for (int ks = 0; ks < 2; ++ks){                 // res: K=64 on x
    bf16x8 a = *reinterpret_cast<const bf16x8*>(xlb + (rowbase + t)*64 + ks*32 + lg*8);
    #pragma unroll
    for (int cf = 0; cf < 4; ++cf){
      bf16x8 bfr = *reinterpret_cast<const bf16x8*>(rp + ((ks*4 + cf)*64 + l)*8);
      ar[cf] = MFMA16(a, bfr, ar[cf]);
    }
  }
  __shared__ float ssum[4][4][16], ssq[4][4][16];
  int tb = w*16 + lg*4;
  #pragma unroll
  for (int cf = 0; cf < 4; ++cf){
    int o = cf*16 + l15;
    float gb = gateb[o], sco = sc2[o], sho = sh2[o];
    float s = 0.f, q = 0.f;
    bf16x4 ov;
    #pragma unroll
    for (int r = 0; r < 4; ++r){
      size_t row = rowbase + tb + r;
      float z = ag[cf][r] + gb;
      float g = 1.f/(1.f + __expf(-z));
      float spv = (float)spm[row*64 + o];
      float tv  = (float)t2[row*64 + o];
      tv = fmaxf(tv*sco + sho, 0.f);
      float val = g*spv + (1.f - g)*tv + ar[cf][r];
      ov[r] = (bf16)val;
      s += val; q += val*val;
    }
    *reinterpret_cast<bf16x4*>(pre + (((size_t)b*64 + o)*512 + n)*64 + tb) = ov;
    s += __shfl_xor(s, 16); s += __shfl_xor(s, 32);
    q += __shfl_xor(q, 16); q += __shfl_xor(q, 32);
    if (lg == 0){ ssum[w][cf][l15] = s; ssq[w][cf][l15] = q; }
  }
  __syncthreads();
  if (tid < 64){
    int cf = tid >> 4, c = tid & 15;
    float s = ssum[0][cf][c]+ssum[1][cf][c]+ssum[2][cf][c]+ssum[3][cf][c];
    float q = ssq[0][cf][c]+ssq[1][cf][c]+ssq[2][cf][c]+ssq[3][cf][c];
    part[(size_t)blk*128 + tid*2]     = s;
    part[(size_t)blk*128 + tid*2 + 1] = q;
  }
}

// ---------------- BN3: read bf16 out_pre, write fp32 d_out ------------------
__global__ __launch_bounds__(256) void k_bn3(const bf16* __restrict__ pre,
    float* __restrict__ out,
    const float* __restrict__ sc, const float* __restrict__ sh){
  size_t total8 = (size_t)BB*CC*NN*TT/8;
  for (size_t i8 = (size_t)blockIdx.x*256 + threadIdx.x; i8 < total8;
       i8 += (size_t)gridDim.x*256){
    bf16x8 v = reinterpret_cast<const bf16x8*>(pre)[i8];
    int o = (int)(i8 >> 12) & 63;                  // n*t = 32768 per (b,o)
    float a = sc[o], bsh = sh[o];
    float4 r0, r1;
    r0.x = (float)v[0]*a + bsh; r0.y = (float)v[1]*a + bsh;
    r0.z = (float)v[2]*a + bsh; r0.w = (float)v[3]*a + bsh;
    r1.x = (float)v[4]*a + bsh; r1.y = (float)v[5]*a + bsh;
    r1.z = (float)v[6]*a + bsh; r1.w = (float)v[7]*a + bsh;
    reinterpret_cast<float4*>(out)[i8*2]     = r0;
    reinterpret_cast<float4*>(out)[i8*2 + 1] = r1;
  }
}

extern "C" void kernel_launch(void* const* d_in, const int* in_sizes, int n_in,
                              void* d_out, int out_size, void* d_ws, size_t ws_size,
                              hipStream_t stream){
  (void)in_sizes; (void)n_in; (void)out_size; (void)ws_size;
  const float* x   = (const float*)d_in[0];
  const float* adj = (const float*)d_in[1];
  const float* cw  = (const float*)d_in[2];
  const float* cb  = (const float*)d_in[3];
  const float* w1  = (const float*)d_in[4];
  // d_in[5] = b1 (cancels in BN1)
  const float* g1  = (const float*)d_in[6];
  const float* be1 = (const float*)d_in[7];
  const float* w2  = (const float*)d_in[8];
  // d_in[9] = b2 (cancels in BN2)
  const float* g2  = (const float*)d_in[10];
  const float* be2 = (const float*)d_in[11];
  const float* gw  = (const float*)d_in[12];
  const float* gb  = (const float*)d_in[13];
  const float* rw  = (const float*)d_in[14];
  // d_in[15] = res_b (cancels in BN3)
  const float* g3  = (const float*)d_in[16];
  const float* be3 = (const float*)d_in[17];
  float* out = (float*)d_out;

  char* ws = (char*)d_ws;
  size_t off = 0;
  auto alloc = [&](size_t bytes)->char*{
    char* p = ws + off; off += (bytes + 255) & ~(size_t)255; return p;
  };
  bf16* xlb  = (bf16*)alloc((size_t)PP*64*2);        // 67MB channel-last x
  bf16* xmt  = (bf16*)alloc((size_t)PP*64*2);        // 67MB; reused as out_pre
  bf16* t1   = (bf16*)alloc((size_t)PP*64*2);        // 67MB; reused as spm
  bf16* t2   = (bf16*)alloc((size_t)PP*64*2);        // 67MB
  bf16* spm  = t1;                                   // alias (t1 dead after conv2)
  bf16* pre  = xmt;                                  // alias (xmt dead after gemm1)
  bf16* adjb = (bf16*)alloc((size_t)KCH*512*512*2);
  bf16* w1p  = (bf16*)alloc(6*2048*2);
  bf16* w2p  = (bf16*)alloc(6*2048*2);
  bf16* cp   = (bf16*)alloc(6*2048*2);
  bf16* gp   = (bf16*)alloc(4*2048*2);
  bf16* rp   = (bf16*)alloc(2*2048*2);
  float* part = (float*)alloc((size_t)8192*128*4);   // shared partials (sequential)
  float* s1sc = (float*)alloc(256); float* s1sh = (float*)alloc(256);
  float* s2sc = (float*)alloc(256); float* s2sh = (float*)alloc(256);
  float* s3sc = (float*)alloc(256); float* s3sh = (float*)alloc(256);

  k_prep <<<dim3(3168), dim3(256), 0, stream>>>(adj, w1, w2, cw, gw, rw,
                                                adjb, w1p, w2p, cp, gp, rp);
  k_xprep<<<dim3(1024), dim3(256), 0, stream>>>(x, xlb, xmt);

  k_conv <<<dim3(8192), dim3(256), 0, stream>>>(xlb, w1p, t1, part, nullptr, nullptr);
  k_stats<<<dim3(64),   dim3(256), 0, stream>>>(part, 8192, g1, be1, s1sc, s1sh);
  k_conv <<<dim3(8192), dim3(256), 0, stream>>>(t1, w2p, t2, part, s1sc, s1sh);
  k_stats<<<dim3(64),   dim3(256), 0, stream>>>(part, 8192, g2, be2, s2sc, s2sh);

  k_gemm1<<<dim3(2048), dim3(512), 0, stream>>>(xmt, adjb, cp, cb, spm);

  k_fusion<<<dim3(8192), dim3(256), 0, stream>>>(spm, t2, xlb, gp, rp,
                                                 s2sc, s2sh, gb, pre, part);
  k_stats<<<dim3(64),   dim3(256), 0, stream>>>(part, 8192, g3, be3, s3sc, s3sh);
  k_bn3  <<<dim3(2048), dim3(256), 0, stream>>>(pre, out, s3sc, s3sh);
}

// Round 9
// 544.436 us; speedup vs baseline: 1.2395x; 1.0072x over previous
//
#include <hip/hip_runtime.h>
#include <hip/hip_bf16.h>
#include <cstdint>

// Problem dims
#define BB 16
#define CC 64
#define NN 512
#define TT 64
#define KCH 3
#define PP (BB*NN*TT)      // 524288 points
#define EPSB 1e-5f

typedef __bf16 bf16;
typedef __bf16 bf16x8 __attribute__((ext_vector_type(8)));
typedef __bf16 bf16x4 __attribute__((ext_vector_type(4)));
typedef float  f32x4  __attribute__((ext_vector_type(4)));

#define MFMA16(A,Bv,Cv) __builtin_amdgcn_mfma_f32_16x16x32_bf16((A),(Bv),(Cv),0,0,0)

__device__ __forceinline__ void gload_lds16(const bf16* g, bf16* l){
  __builtin_amdgcn_global_load_lds(
      (const __attribute__((address_space(1))) void*)g,
      (__attribute__((address_space(3))) void*)l, 16, 0, 0);
}

// ---------------- prep (merged): adjb transpose + weight fragment prep -----
__global__ __launch_bounds__(256) void k_prep(const float* __restrict__ adj,
    const float* __restrict__ w1, const float* __restrict__ w2,
    const float* __restrict__ cw, const float* __restrict__ gw,
    const float* __restrict__ rw, bf16* __restrict__ adjb,
    bf16* __restrict__ w1p, bf16* __restrict__ w2p, bf16* __restrict__ cp,
    bf16* __restrict__ gp, bf16* __restrict__ rp){
  int blk = blockIdx.x, tid = threadIdx.x;
  if (blk < 3072){
    int idx = blk*256 + tid;
    int m = idx & 511, n = (idx >> 9) & 511, k = idx >> 18;
    adjb[idx] = (bf16)adj[((size_t)(k*512 + m))*512 + n];
    return;
  }
  int e0 = (blk - 3072)*256 + tid;                  // [0, 24576)
  if (e0 < 12288){                                  // K=192 groups (conv & cheb)
    int e = e0;
    int j = e&7, lane = (e>>3)&63, cf = (e>>9)&3, ks = e>>11;
    int k = ks*32 + (lane>>4)*8 + j, col = cf*16 + (lane&15);
    int kk = k >> 6, i = k & 63;
    w1p[e] = (bf16)w1[(col*64 + i)*3 + kk];
    w2p[e] = (bf16)w2[(col*64 + i)*3 + kk];
    cp[e]  = (bf16)cw[((size_t)kk*64 + i)*64 + col];
  } else if (e0 < 20480){                           // K=128 (gate)
    int e = e0 - 12288;
    int j = e&7, lane = (e>>3)&63, cf = (e>>9)&3, ks = e>>11;
    int k = ks*32 + (lane>>4)*8 + j, col = cf*16 + (lane&15);
    gp[e] = (bf16)gw[col*128 + k];
  } else {                                          // K=64 (res)
    int e = e0 - 20480;
    int j = e&7, lane = (e>>3)&63, cf = (e>>9)&3, ks = e>>11;
    int k = ks*32 + (lane>>4)*8 + j, col = cf*16 + (lane&15);
    rp[e] = (bf16)rw[col*64 + k];
  }
}

// ---------------- fused x prep: one read of x -> xlb AND xmt ----------------
__global__ __launch_bounds__(256) void k_xprep(const float* __restrict__ x,
    bf16* __restrict__ xlb, bf16* __restrict__ xmt){
  __shared__ bf16 T[32768];               // 64KB
  int bid = blockIdx.x;
  int b = bid >> 6, i0 = ((bid >> 3) & 7)*8, n0 = (bid & 7)*64;
  int tid = threadIdx.x;
  #pragma unroll 4
  for (int it = 0; it < 32; ++it){
    int flat = it*256 + tid;              // [0,8192)
    int t4 = flat & 15, n = (flat >> 4) & 63, i = flat >> 10;
    float4 v = *reinterpret_cast<const float4*>(
        x + ((size_t)((b*64 + i0 + i)*512) + (n0 + n))*64 + t4*4);
    int s = t4 ^ ((n + 2*i) & 15);
    bf16x4 pk; pk[0]=(bf16)v.x; pk[1]=(bf16)v.y; pk[2]=(bf16)v.z; pk[3]=(bf16)v.w;
    *reinterpret_cast<bf16x4*>(&T[(i*64 + n)*64 + s*4]) = pk;
  }
  __syncthreads();
  // xmt emission
  #pragma unroll 4
  for (int it = 0; it < 16; ++it){
    int flat = it*256 + tid;              // [0,4096)
    int mc = flat & 7, i = (flat >> 3) & 7, t = flat >> 6;
    bf16x8 o;
    #pragma unroll
    for (int e = 0; e < 8; ++e){
      int m = mc*8 + e;
      int s = (t >> 2) ^ ((m + 2*i) & 15);
      o[e] = T[(i*64 + m)*64 + s*4 + (t & 3)];
    }
    *reinterpret_cast<bf16x8*>(
        &xmt[((size_t)((b*64 + t)*64) + i0 + i)*512 + n0 + mc*8]) = o;
  }
  // xlb emission
  #pragma unroll 4
  for (int it = 0; it < 16; ++it){
    int flat = it*256 + tid;              // [0,4096)
    int t = flat & 63, n = flat >> 6;
    bf16x8 o;
    #pragma unroll
    for (int e = 0; e < 8; ++e){
      int s = (t >> 2) ^ ((n + 2*e) & 15);
      o[e] = T[(e*64 + n)*64 + s*4 + (t & 3)];
    }
    *reinterpret_cast<bf16x8*>(
        &xlb[(((size_t)b*512 + n0 + n)*64 + t)*64 + i0]) = o;
  }
}

// ---------------- temporal conv (1x3) as tall GEMM; optional BN+relu on load
__global__ __launch_bounds__(256,4) void k_conv(const bf16* __restrict__ in,
    const bf16* __restrict__ wp, bf16* __restrict__ outp, float* __restrict__ part,
    const float* __restrict__ sc, const float* __restrict__ sh){
  int tid = threadIdx.x, w = tid >> 6, l = tid & 63, l15 = l & 15, lg = l >> 4;
  int blk = blockIdx.x;
  size_t rowbase = (size_t)blk * 64;
  const bf16* xr = in + rowbase * 64;
  int t = w*16 + l15;
  f32x4 acc[4] = {};
  #pragma unroll
  for (int ks = 0; ks < 6; ++ks){
    int dt = ks >> 1, kh = ks & 1;
    int ts = t + dt - 1;
    bf16x8 a = {};
    if (ts >= 0 && ts < 64){
      a = *reinterpret_cast<const bf16x8*>(xr + ts*64 + kh*32 + lg*8);
      if (sc){                                  // BN1+relu applied on load
        int i0 = kh*32 + lg*8;
        #pragma unroll
        for (int e = 0; e < 8; ++e){
          float f = (float)a[e]*sc[i0+e] + sh[i0+e];
          a[e] = (bf16)fmaxf(f, 0.f);
        }
      }
    }
    #pragma unroll
    for (int cf = 0; cf < 4; ++cf){
      bf16x8 bfr = *reinterpret_cast<const bf16x8*>(wp + ((ks*4 + cf)*64 + l)*8);
      acc[cf] = MFMA16(a, bfr, acc[cf]);
    }
  }
  __shared__ float ssum[4][4][16], ssq[4][4][16];
  #pragma unroll
  for (int cf = 0; cf < 4; ++cf){
    int o = cf*16 + l15;
    float s = 0.f, q = 0.f;
    #pragma unroll
    for (int r = 0; r < 4; ++r){
      float vv = acc[cf][r];
      int to = w*16 + lg*4 + r;
      outp[(rowbase + to)*64 + o] = (bf16)vv;
      s += vv; q += vv*vv;
    }
    s += __shfl_xor(s, 16); s += __shfl_xor(s, 32);
    q += __shfl_xor(q, 16); q += __shfl_xor(q, 32);
    if (lg == 0){ ssum[w][cf][l15] = s; ssq[w][cf][l15] = q; }
  }
  __syncthreads();
  if (tid < 64){
    int cf = tid >> 4, c = tid & 15;
    float s = ssum[0][cf][c]+ssum[1][cf][c]+ssum[2][cf][c]+ssum[3][cf][c];
    float q = ssq[0][cf][c]+ssq[1][cf][c]+ssq[2][cf][c]+ssq[3][cf][c];
    part[(size_t)blk*128 + tid*2]     = s;
    part[(size_t)blk*128 + tid*2 + 1] = q;
  }
}

// ---------------- BN stats finalize: partials -> scale/shift ----------------
__global__ __launch_bounds__(256) void k_stats(const float* __restrict__ part, int nb,
    const float* __restrict__ g, const float* __restrict__ be,
    float* __restrict__ sc, float* __restrict__ sh){
  int c = blockIdx.x, tid = threadIdx.x;
  float s = 0.f, q = 0.f;
  for (int i = tid; i < nb; i += 256){
    s += part[(size_t)i*128 + c*2];
    q += part[(size_t)i*128 + c*2 + 1];
  }
  __shared__ float rs[256], rq[256];
  rs[tid] = s; rq[tid] = q; __syncthreads();
  for (int st = 128; st > 0; st >>= 1){
    if (tid < st){ rs[tid] += rs[tid+st]; rq[tid] += rq[tid+st]; }
    __syncthreads();
  }
  if (tid == 0){
    float cnt = (float)PP;
    float mean = rs[0]/cnt, var = rq[0]/cnt - mean*mean;
    float r = rsqrtf(var + EPSB);
    sc[c] = g[c]*r;
    sh[c] = be[c] - mean*g[c]*r;
  }
}

// ---------------- fused GEMM1+cheb: spm[(b,n,t)][o] ------------------------
// v8: SINGLE barrier per K-step. Per step: [lgkm(0) seal own t-1 reads] ->
// barrier (rendezvous: buf[(t+2)%3] provably free) -> stage(t+2) -> counted
// vmcnt (tile t landed) -> ds_reads -> MFMA. 3 buffers, 2-deep prefetch,
// 80KB LDS, full 32KB VT, 2 extra barriers per kk boundary only.
__global__ __launch_bounds__(512,4) void k_gemm1(const bf16* __restrict__ xmt,
    const bf16* __restrict__ adjb, const bf16* __restrict__ cp,
    const float* __restrict__ cb, bf16* __restrict__ spm){
  __shared__ bf16 As[3][4096];          // [buf][row128][chunk4 swz][8]
  __shared__ bf16 Bs[3][4096];
  __shared__ bf16 VT[128*128];          // 32KB; VT[n][j] swz; reused SP[256][64]

  int tid = threadIdx.x, w = tid >> 6, l = tid & 63, l15 = l & 15, lg = l >> 4;
  int wr = w >> 2, wc = w & 3;          // j-half, n-quarter

  // bijective XCD swizzle over 2048 blocks; nt innermost (A-panel shared by 4)
  int orig = blockIdx.x;
  int wg = (orig & 7) * 256 + (orig >> 3);
  int jt = wg >> 2, nt = wg & 3;
  int J0 = jt*128, N0 = nt*128;

  const bf16* aglob = xmt + (size_t)J0*512;
  const bf16* bbase = adjb + (size_t)N0*512;

  // staging: thread -> (row sr, chunk sc); global chunk XOR-permuted
  int sr = tid >> 2, sc = tid & 3;
  int scg = sc ^ (sr & 3) ^ ((sr >> 2) & 3);
  size_t soff = (size_t)sr*512 + scg*8;

  auto stage = [&](int t){              // 2 gload instrs per wave (vmcnt +2)
    int buf = t % 3;
    const bf16* bg = bbase + (size_t)(t >> 4)*(512*512);
    int m0 = (t & 15)*32;
    gload_lds16(aglob + soff + m0, &As[buf][tid*8]);
    gload_lds16(bg    + soff + m0, &Bs[buf][tid*8]);
  };

  // LDS read offsets (elements), loop-invariant
  int aoff[4], boff[2];
  #pragma unroll
  for (int rf = 0; rf < 4; ++rf){
    int row = wr*64 + rf*16 + l15;
    aoff[rf] = row*32 + ((lg ^ (row & 3) ^ ((row >> 2) & 3))*8);
  }
  #pragma unroll
  for (int cf = 0; cf < 2; ++cf){
    int row = wc*32 + cf*16 + l15;
    boff[cf] = row*32 + ((lg ^ (row & 3) ^ ((row >> 2) & 3))*8);
  }

  f32x4 acc[4][2] = {};
  f32x4 acc2[2][4] = {};

  stage(0); stage(1);
  for (int t = 0; t < 48; ++t){
    // seal own LDS reads from step t-1 (cheap: MFMAs already consumed them),
    // then ONE rendezvous barrier: after it, buf[(t+2)%3] is free to overwrite
    asm volatile("s_waitcnt lgkmcnt(0)" ::: "memory");
    __builtin_amdgcn_sched_barrier(0);
    __builtin_amdgcn_s_barrier();
    if (t < 46) stage(t+2);
    // counted vmcnt: newest 4 outstanding = stage(t+1)+stage(t+2) => tile t done
    if (t < 46)       asm volatile("s_waitcnt vmcnt(4)" ::: "memory");
    else if (t == 46) asm volatile("s_waitcnt vmcnt(2)" ::: "memory");
    else              asm volatile("s_waitcnt vmcnt(0)" ::: "memory");
    __builtin_amdgcn_sched_barrier(0);

    int buf = t % 3;
    bf16x8 a[4], bb[2];
    #pragma unroll
    for (int rf = 0; rf < 4; ++rf)
      a[rf] = *reinterpret_cast<const bf16x8*>(&As[buf][aoff[rf]]);
    #pragma unroll
    for (int cf = 0; cf < 2; ++cf)
      bb[cf] = *reinterpret_cast<const bf16x8*>(&Bs[buf][boff[cf]]);
    #pragma unroll
    for (int rf = 0; rf < 4; ++rf)
      #pragma unroll
      for (int cf = 0; cf < 2; ++cf)
        acc[rf][cf] = MFMA16(a[rf], bb[cf], acc[rf][cf]);

    if ((t & 15) == 15){
      int kk = t >> 4;
      // full V-tile dump: wave owns j-rows wr*64.., n-cols wc*32..
      #pragma unroll
      for (int rf = 0; rf < 4; ++rf){
        int jb = wr*8 + rf*2 + (lg >> 1);         // j0 = wr*64+rf*16+lg*4
        #pragma unroll
        for (int cf = 0; cf < 2; ++cf){
          int nh = wc*32 + cf*16 + l15;           // n in [0,128)
          bf16x4 pk;
          #pragma unroll
          for (int r = 0; r < 4; ++r) pk[r] = (bf16)acc[rf][cf][r];
          *reinterpret_cast<bf16x4*>(
              &VT[nh*128 + ((jb ^ (nh & 15)) << 3) + ((lg & 1) << 2)]) = pk;
          acc[rf][cf] = (f32x4){0.f, 0.f, 0.f, 0.f};
        }
      }
      asm volatile("s_waitcnt lgkmcnt(0)" ::: "memory");
      __builtin_amdgcn_sched_barrier(0);
      __builtin_amdgcn_s_barrier();               // all dumps visible

      // cheb contraction, single phase: wave -> t_out = w>>2, n-grp = w&3
      // (VT reads sealed by next iteration's top lgkm(0)+barrier)
      #pragma unroll
      for (int ks2 = 0; ks2 < 2; ++ks2){
        bf16x8 bc[4];
        #pragma unroll
        for (int cf = 0; cf < 4; ++cf)
          bc[cf] = *reinterpret_cast<const bf16x8*>(
              cp + (((kk*2 + ks2)*4 + cf)*64 + l)*8);
        #pragma unroll
        for (int h = 0; h < 2; ++h){
          int nh = h*64 + (w & 3)*16 + l15;
          int jb = (w >> 2)*8 + ks2*4 + lg;
          bf16x8 a2 = *reinterpret_cast<const bf16x8*>(
              &VT[nh*128 + ((jb ^ (nh & 15)) << 3)]);
          #pragma unroll
          for (int cf = 0; cf < 4; ++cf)
            acc2[h][cf] = MFMA16(a2, bc[cf], acc2[h][cf]);
        }
      }
    }
  }

  __syncthreads();                      // all contraction reads done before SP
  // epilogue: SP[row=(t_out*128+n)][o] = acc2 + cheb_b, then coalesced store
  bf16* SP = VT;
  float cbv[4];
  #pragma unroll
  for (int cf = 0; cf < 4; ++cf) cbv[cf] = cb[cf*16 + l15];
  int b = jt >> 5, t0 = (jt & 31)*2;
  #pragma unroll
  for (int h = 0; h < 2; ++h){
    int rowb = (w >> 2)*128 + h*64 + (w & 3)*16 + lg*4;
    #pragma unroll
    for (int cf = 0; cf < 4; ++cf){
      int o = cf*16 + l15;
      #pragma unroll
      for (int r = 0; r < 4; ++r)
        SP[(rowb + r)*64 + o] = (bf16)(acc2[h][cf][r] + cbv[cf]);
    }
  }
  __syncthreads();
  #pragma unroll
  for (int q = 0; q < 4; ++q){
    int flat = q*512 + tid;             // 2048 chunks of 8 elems
    int row = flat >> 3, oc = (flat & 7)*8;
    int tl = row >> 7, n = row & 127;
    bf16x8 vv = *reinterpret_cast<const bf16x8*>(&SP[row*64 + oc]);
    *reinterpret_cast<bf16x8*>(
        &spm[(((size_t)b*512 + N0 + n)*64 + (t0 + tl))*64 + oc]) = vv;
  }
}

// ---------------- fusion: gate/res MFMA + combine; writes bf16 out_pre -----
__global__ __launch_bounds__(256,4) void k_fusion(const bf16* __restrict__ spm,
    const bf16* __restrict__ t2, const bf16* __restrict__ xlb,
    const bf16* __restrict__ gp, const bf16* __restrict__ rp,
    const float* __restrict__ sc2, const float* __restrict__ sh2,
    const float* __restrict__ gateb, bf16* __restrict__ pre,
    float* __restrict__ part){
  int tid = threadIdx.x, w = tid >> 6, l = tid & 63, l15 = l & 15, lg = l >> 4;
  int blk = blockIdx.x;
  int b = blk >> 9, n = blk & 511;
  size_t rowbase = (size_t)blk * 64;
  int t = w*16 + l15;
  f32x4 ag[4] = {}, ar[4] = {};
  #pragma unroll
  for (int ks = 0; ks < 4; ++ks){                 // gate: K=128 = [spatial|t2bn]
    bf16x8 a;
    if (ks < 2){
      a = *reinterpret_cast<const bf16x8*>(spm + (rowbase + t)*64 + ks*32 + lg*8);
    } else {
      int i0 = (ks-2)*32 + lg*8;
      bf16x8 raw = *reinterpret_cast<const bf16x8*>(t2 + (rowbase + t)*64 + i0);
      #pragma unroll
      for (int e = 0; e < 8; ++e){
        float f = (float)raw[e]*sc2[i0+e] + sh2[i0+e];
        a[e] = (bf16)fmaxf(f, 0.f);
      }
    }
    #pragma unroll
    for (int cf = 0; cf < 4; ++cf){
      bf16x8 bfr = *reinterpret_cast<const bf16x8*>(gp + ((ks*4 + cf)*64 + l)*8);
      ag[cf] = MFMA16(a, bfr, ag[cf]);
    }
  }
  #pragma unroll
  for (int ks = 0; ks < 2; ++ks){                 // res: K=64 on x
    bf16x8 a = *reinterpret_cast<const bf16x8*>(xlb + (rowbase + t)*64 + ks*32 + lg*8);
    #pragma unroll
    for (int cf = 0; cf < 4; ++cf){
      bf16x8 bfr = *reinterpret_cast<const bf16x8*>(rp + ((ks*4 + cf)*64 + l)*8);
      ar[cf] = MFMA16(a, bfr, ar[cf]);
    }
  }
  __shared__ float ssum[4][4][16], ssq[4][4][16];
  int tb = w*16 + lg*4;
  #pragma unroll
  for (int cf = 0; cf < 4; ++cf){
    int o = cf*16 + l15;
    float gb = gateb[o], sco = sc2[o], sho = sh2[o];
    float s = 0.f, q = 0.f;
    bf16x4 ov;
    #pragma unroll
    for (int r = 0; r < 4; ++r){
      size_t row = rowbase + tb + r;
      float z = ag[cf][r] + gb;
      float g = 1.f/(1.f + __expf(-z));
      float spv = (float)spm[row*64 + o];
      float tv  = (float)t2[row*64 + o];
      tv = fmaxf(tv*sco + sho, 0.f);
      float val = g*spv + (1.f - g)*tv + ar[cf][r];
      ov[r] = (bf16)val;
      s += val; q += val*val;
    }
    *reinterpret_cast<bf16x4*>(pre + (((size_t)b*64 + o)*512 + n)*64 + tb) = ov;
    s += __shfl_xor(s, 16); s += __shfl_xor(s, 32);
    q += __shfl_xor(q, 16); q += __shfl_xor(q, 32);
    if (lg == 0){ ssum[w][cf][l15] = s; ssq[w][cf][l15] = q; }
  }
  __syncthreads();
  if (tid < 64){
    int cf = tid >> 4, c = tid & 15;
    float s = ssum[0][cf][c]+ssum[1][cf][c]+ssum[2][cf][c]+ssum[3][cf][c];
    float q = ssq[0][cf][c]+ssq[1][cf][c]+ssq[2][cf][c]+ssq[3][cf][c];
    part[(size_t)blk*128 + tid*2]     = s;
    part[(size_t)blk*128 + tid*2 + 1] = q;
  }
}

// ---------------- BN3: read bf16 out_pre, write fp32 d_out ------------------
__global__ __launch_bounds__(256) void k_bn3(const bf16* __restrict__ pre,
    float* __restrict__ out,
    const float* __restrict__ sc, const float* __restrict__ sh){
  size_t total8 = (size_t)BB*CC*NN*TT/8;
  for (size_t i8 = (size_t)blockIdx.x*256 + threadIdx.x; i8 < total8;
       i8 += (size_t)gridDim.x*256){
    bf16x8 v = reinterpret_cast<const bf16x8*>(pre)[i8];
    int o = (int)(i8 >> 12) & 63;                  // n*t = 32768 per (b,o)
    float a = sc[o], bsh = sh[o];
    float4 r0, r1;
    r0.x = (float)v[0]*a + bsh; r0.y = (float)v[1]*a + bsh;
    r0.z = (float)v[2]*a + bsh; r0.w = (float)v[3]*a + bsh;
    r1.x = (float)v[4]*a + bsh; r1.y = (float)v[5]*a + bsh;
    r1.z = (float)v[6]*a + bsh; r1.w = (float)v[7]*a + bsh;
    reinterpret_cast<float4*>(out)[i8*2]     = r0;
    reinterpret_cast<float4*>(out)[i8*2 + 1] = r1;
  }
}

extern "C" void kernel_launch(void* const* d_in, const int* in_sizes, int n_in,
                              void* d_out, int out_size, void* d_ws, size_t ws_size,
                              hipStream_t stream){
  (void)in_sizes; (void)n_in; (void)out_size; (void)ws_size;
  const float* x   = (const float*)d_in[0];
  const float* adj = (const float*)d_in[1];
  const float* cw  = (const float*)d_in[2];
  const float* cb  = (const float*)d_in[3];
  const float* w1  = (const float*)d_in[4];
  // d_in[5] = b1 (cancels in BN1)
  const float* g1  = (const float*)d_in[6];
  const float* be1 = (const float*)d_in[7];
  const float* w2  = (const float*)d_in[8];
  // d_in[9] = b2 (cancels in BN2)
  const float* g2  = (const float*)d_in[10];
  const float* be2 = (const float*)d_in[11];
  const float* gw  = (const float*)d_in[12];
  const float* gb  = (const float*)d_in[13];
  const float* rw  = (const float*)d_in[14];
  // d_in[15] = res_b (cancels in BN3)
  const float* g3  = (const float*)d_in[16];
  const float* be3 = (const float*)d_in[17];
  float* out = (float*)d_out;

  char* ws = (char*)d_ws;
  size_t off = 0;
  auto alloc = [&](size_t bytes)->char*{
    char* p = ws + off; off += (bytes + 255) & ~(size_t)255; return p;
  };
  bf16* xlb  = (bf16*)alloc((size_t)PP*64*2);        // 67MB channel-last x
  bf16* xmt  = (bf16*)alloc((size_t)PP*64*2);        // 67MB; reused as out_pre
  bf16* t1   = (bf16*)alloc((size_t)PP*64*2);        // 67MB; reused as spm
  bf16* t2   = (bf16*)alloc((size_t)PP*64*2);        // 67MB
  bf16* spm  = t1;                                   // alias (t1 dead after conv2)
  bf16* pre  = xmt;                                  // alias (xmt dead after gemm1)
  bf16* adjb = (bf16*)alloc((size_t)KCH*512*512*2);
  bf16* w1p  = (bf16*)alloc(6*2048*2);
  bf16* w2p  = (bf16*)alloc(6*2048*2);
  bf16* cp   = (bf16*)alloc(6*2048*2);
  bf16* gp   = (bf16*)alloc(4*2048*2);
  bf16* rp   = (bf16*)alloc(2*2048*2);
  float* part = (float*)alloc((size_t)8192*128*4);   // shared partials (sequential)
  float* s1sc = (float*)alloc(256); float* s1sh = (float*)alloc(256);
  float* s2sc = (float*)alloc(256); float* s2sh = (float*)alloc(256);
  float* s3sc = (float*)alloc(256); float* s3sh = (float*)alloc(256);

  k_prep <<<dim3(3168), dim3(256), 0, stream>>>(adj, w1, w2, cw, gw, rw,
                                                adjb, w1p, w2p, cp, gp, rp);
  k_xprep<<<dim3(1024), dim3(256), 0, stream>>>(x, xlb, xmt);

  k_conv <<<dim3(8192), dim3(256), 0, stream>>>(xlb, w1p, t1, part, nullptr, nullptr);
  k_stats<<<dim3(64),   dim3(256), 0, stream>>>(part, 8192, g1, be1, s1sc, s1sh);
  k_conv <<<dim3(8192), dim3(256), 0, stream>>>(t1, w2p, t2, part, s1sc, s1sh);
  k_stats<<<dim3(64),   dim3(256), 0, stream>>>(part, 8192, g2, be2, s2sc, s2sh);

  k_gemm1<<<dim3(2048), dim3(512), 0, stream>>>(xmt, adjb, cp, cb, spm);

  k_fusion<<<dim3(8192), dim3(256), 0, stream>>>(spm, t2, xlb, gp, rp,
                                                 s2sc, s2sh, gb, pre, part);
  k_stats<<<dim3(64),   dim3(256), 0, stream>>>(part, 8192, g3, be3, s3sc, s3sh);
  k_bn3  <<<dim3(2048), dim3(256), 0, stream>>>(pre, out, s3sc, s3sh);
}